// Round 8
// baseline (95.507 us; speedup 1.0000x reference)
//
#include <hip/hip_runtime.h>
#include <hip/hip_bf16.h>

#define TB   8192   // B*C*N bags
#define WW   32     // words per bag
#define DD   512    // d_model
#define DKK  64     // attention dim
#define CCC  4      // max cross

#define CONV_BLKS   2000
#define CONV_CHUNKS 2048000   // 32000*512/8

using bf16x8 = __attribute__((ext_vector_type(8))) short;
using f32x4  = __attribute__((ext_vector_type(4))) float;

__device__ __forceinline__ unsigned short f2bf(float x) {
    union { float f; unsigned u; } u;
    u.f = x;
    unsigned r = u.u + 0x7fffu + ((u.u >> 16) & 1u);
    return (unsigned short)(r >> 16);
}

__device__ __forceinline__ bf16x8 make_frag(float4 x, float4 y) {
    union { bf16x8 v; unsigned short s[8]; } u;
    u.s[0] = f2bf(x.x); u.s[1] = f2bf(x.y); u.s[2] = f2bf(x.z); u.s[3] = f2bf(x.w);
    u.s[4] = f2bf(y.x); u.s[5] = f2bf(y.y); u.s[6] = f2bf(y.z); u.s[7] = f2bf(y.w);
    return u.v;
}

// fma 8 bf16 elems (packed) into fp32 accumulators: cx[j] += s * elem[j]
__device__ __forceinline__ void bfx8_fma(float* cx, bf16x8 r, float s) {
    union { bf16x8 v; unsigned u[4]; } u; u.v = r;
    #pragma unroll
    for (int j = 0; j < 4; ++j) {
        float lo = __uint_as_float(u.u[j] << 16);
        float hi = __uint_as_float(u.u[j] & 0xffff0000u);
        cx[2 * j]     += s * lo;
        cx[2 * j + 1] += s * hi;
    }
}

// ---------------- fused preprocessing ----------------
// blocks [0, CONV_BLKS)       : emb fp32 -> bf16 (grid-stride, 4 chunks/thread)
// blocks [CONV_BLKS, +64)     : prep (q GEMV + hidden copy)
// blocks [CONV_BLKS+64, +128) : pack W_pre fragments
__global__ __launch_bounds__(256) void preproc_kernel(
    const float* __restrict__ emb,
    unsigned short* __restrict__ embh,
    const float* __restrict__ con_hidden,  // [64][512]
    const float* __restrict__ W_q,         // [512][64]
    float* __restrict__ qout,              // [64][64]
    float* __restrict__ hid_out,           // [64][512]
    const float* __restrict__ W_pre,       // [512][64]
    bf16x8* __restrict__ wb)               // 64 frags * 64 lanes
{
    const int blk = blockIdx.x;
    const int tid = threadIdx.x;
    if (blk < CONV_BLKS) {
        // 2048000 chunks / (2000*256 threads) = exactly 4 per thread
        size_t idx = (size_t)blk * 256 + tid;
        #pragma unroll 4
        for (int it = 0; it < 4; ++it) {
            const size_t i = idx * 8;
            const float4* p = (const float4*)(emb + i);
            float4 a = p[0], b = p[1];
            *(bf16x8*)(embh + i) = make_frag(a, b);
            idx += (size_t)CONV_BLKS * 256;
        }
    } else if (blk < CONV_BLKS + 64) {
        if (tid >= 64) return;
        const int b = blk - CONV_BLKS;
        const int k = tid;
        const float* h = con_hidden + b * DD;
        float acc = 0.0f;
        #pragma unroll 8
        for (int d = 0; d < DD; ++d) acc += h[d] * W_q[d * DKK + k];
        qout[b * DKK + k] = acc;
        const float4* src = (const float4*)h;
        float4* dst = (float4*)(hid_out + b * DD);
        for (int i = k; i < DD / 4; i += 64) dst[i] = src[i];
    } else {
        if (tid >= 64) return;
        const int fb = blk - CONV_BLKS - 64;   // ks*4 + nt
        const int ks = fb >> 2, nt = fb & 3;
        const int lr = tid & 15, lg = tid >> 4;
        union { bf16x8 v; unsigned short s[8]; } u;
        #pragma unroll
        for (int j = 0; j < 8; ++j) {
            int k = ks * 32 + lg * 8 + j;
            u.s[j] = f2bf(W_pre[k * DKK + nt * 16 + lr]);
        }
        wb[fb * 64 + tid] = u.v;
    }
}

// ---------------- main bag kernel: 8 waves/block, wb in LDS ----------------
__global__ __launch_bounds__(512, 4) void bag_kernel(
    const int* __restrict__ token_ids,     // [8192][32]
    const int* __restrict__ node_lengths,  // [8192]
    const int* __restrict__ node_sizes,    // [256]
    const int* __restrict__ cross_lengths, // [64]
    const unsigned short* __restrict__ embh, // [32000][512] bf16, row 0 zeros
    const float* __restrict__ b_pre,       // [64]
    const float* __restrict__ v,           // [64]
    const float* __restrict__ q,           // [64][64]
    const bf16x8* __restrict__ wb,         // packed W_pre fragments (64 KB)
    float* __restrict__ out)               // [8192][512]
{
    const int tid  = threadIdx.x;
    const int wid  = tid >> 6;
    const int lane = tid & 63;
    const int t = blockIdx.x * 8 + wid;
    const int b = t >> 7, cn = t & 127, c = cn >> 5, n = cn & 31;
    const int lr = lane & 15, lg = lane >> 4;

    __shared__ bf16x8 swb[4096];   // 64 KB shared W_pre fragments

    const int L = node_lengths[t];
    const int* toks = token_ids + t * WW;

    // lane w (<32) holds masked token id of word w (emb row 0 is all-zero)
    int my_tok = 0;
    if (lane < 32 && lane < L) my_tok = toks[lane];

    // A-row pointers for the two M-tiles (words lr and 16+lr)
    const int tok0 = __shfl(my_tok, lr);
    const int tok1 = __shfl(my_tok, 16 + lr);
    const unsigned short* hp0 = embh + ((size_t)tok0 << 9) + lg * 8;
    const unsigned short* hp1 = embh + ((size_t)tok1 << 9) + lg * 8;

    bf16x8 A0[8], A1[8], Bs[2][4];
    auto loadA = [&](int ks, int sl) {
        A0[sl] = *(const bf16x8*)(hp0 + ks * 32);
        A1[sl] = *(const bf16x8*)(hp1 + ks * 32);
    };
    auto loadB = [&](int ks, int sl) {
        #pragma unroll
        for (int nt = 0; nt < 4; ++nt)
            Bs[sl][nt] = swb[(ks * 4 + nt) * 64 + lane];
    };

    // 8-deep gather prologue BEFORE the LDS fill so it hides under the fill
    loadA(0, 0); loadA(1, 1); loadA(2, 2); loadA(3, 3);
    loadA(4, 4); loadA(5, 5); loadA(6, 6); loadA(7, 7);
    asm volatile("" ::: "memory");

    // cooperative fill of wb -> LDS (4096 x 16B, 8 iters/thread)
    #pragma unroll
    for (int i = tid; i < 4096; i += 512) swb[i] = wb[i];
    __syncthreads();            // the ONLY block-wide barrier

    f32x4 acc[2][4];
    #pragma unroll
    for (int mt = 0; mt < 2; ++mt)
        #pragma unroll
        for (int nt = 0; nt < 4; ++nt)
            acc[mt][nt] = (f32x4){0.f, 0.f, 0.f, 0.f};

    loadB(0, 0);
    asm volatile("" ::: "memory");

    // ---- pre = bag @ W_pre via MFMA: A 8-deep (global), B 2-deep (LDS) ----
    #pragma unroll
    for (int ks = 0; ks < 16; ++ks) {
        bf16x8 a0 = A0[ks & 7], a1 = A1[ks & 7];   // consume before slot reuse
        if (ks + 8 < 16) loadA(ks + 8, ks & 7);
        if (ks + 1 < 16) loadB(ks + 1, (ks + 1) & 1);
        asm volatile("" ::: "memory");             // loads cannot sink past here
        const int bs = ks & 1;
        acc[0][0] = __builtin_amdgcn_mfma_f32_16x16x32_bf16(a0, Bs[bs][0], acc[0][0], 0, 0, 0);
        acc[0][1] = __builtin_amdgcn_mfma_f32_16x16x32_bf16(a0, Bs[bs][1], acc[0][1], 0, 0, 0);
        acc[0][2] = __builtin_amdgcn_mfma_f32_16x16x32_bf16(a0, Bs[bs][2], acc[0][2], 0, 0, 0);
        acc[0][3] = __builtin_amdgcn_mfma_f32_16x16x32_bf16(a0, Bs[bs][3], acc[0][3], 0, 0, 0);
        acc[1][0] = __builtin_amdgcn_mfma_f32_16x16x32_bf16(a1, Bs[bs][0], acc[1][0], 0, 0, 0);
        acc[1][1] = __builtin_amdgcn_mfma_f32_16x16x32_bf16(a1, Bs[bs][1], acc[1][1], 0, 0, 0);
        acc[1][2] = __builtin_amdgcn_mfma_f32_16x16x32_bf16(a1, Bs[bs][2], acc[1][2], 0, 0, 0);
        acc[1][3] = __builtin_amdgcn_mfma_f32_16x16x32_bf16(a1, Bs[bs][3], acc[1][3], 0, 0, 0);
    }

    // ---- kick off context-row prefetch NOW: addresses don't need scores ----
    const int d0 = lane * 8;
    bf16x8 R[6];
    auto cissue = [&](int w, int sl) {
        int tk = __shfl(my_tok, w);
        R[sl] = *(const bf16x8*)(embh + ((size_t)tk << 9) + d0);
    };
    cissue(0, 0); cissue(1, 1); cissue(2, 2);
    cissue(3, 3); cissue(4, 4); cissue(5, 5);
    asm volatile("" ::: "memory");   // in flight across energy+softmax

    // ---- energy: e[w] = sum_k tanh(pre + b_pre + q) * v  (all in registers) ----
    // C layout: col = nt*16 + lr ; row(word) = mt*16 + lg*4 + r
    float qb[4], vv[4];
    #pragma unroll
    for (int nt = 0; nt < 4; ++nt) {
        int cidx = nt * 16 + lr;
        qb[nt] = q[b * DKK + cidx] + b_pre[cidx];
        vv[nt] = v[cidx];
    }
    float ev[8];   // ev[mt*4+r] = e[mt*16 + lg*4 + r], replicated across lr
    #pragma unroll
    for (int mt = 0; mt < 2; ++mt) {
        #pragma unroll
        for (int r = 0; r < 4; ++r) {
            float s = 0.0f;
            #pragma unroll
            for (int nt = 0; nt < 4; ++nt) {
                float pre = acc[mt][nt][r] + qb[nt];
                float ez = __expf(2.0f * pre);                 // tanh via exp
                float th = 1.0f - 2.0f * __builtin_amdgcn_rcpf(ez + 1.0f);
                s += th * vv[nt];
            }
            s += __shfl_xor(s, 1);
            s += __shfl_xor(s, 2);
            s += __shfl_xor(s, 4);
            s += __shfl_xor(s, 8);   // every lane in the lg-group has e[w]
            ev[mt * 4 + r] = s;
        }
    }

    // ---- softmax over 32 word slots, wave-local ----
    float mx = ev[0];
    #pragma unroll
    for (int j = 1; j < 8; ++j) mx = fmaxf(mx, ev[j]);
    mx = fmaxf(mx, __shfl_xor(mx, 16));
    mx = fmaxf(mx, __shfl_xor(mx, 32));
    float sc[8], sm = 0.0f;
    #pragma unroll
    for (int j = 0; j < 8; ++j) { sc[j] = __expf(ev[j] - mx); sm += sc[j]; }
    sm += __shfl_xor(sm, 16);
    sm += __shfl_xor(sm, 32);
    const float inv = 1.0f / sm;
    #pragma unroll
    for (int j = 0; j < 8; ++j) sc[j] *= inv;

    // ---- context: lane owns 8 consecutive d's; 6-deep pipelined gather ----
    float cx[8];
    #pragma unroll
    for (int j = 0; j < 8; ++j) cx[j] = 0.0f;

    #pragma unroll
    for (int w = 0; w < WW; ++w) {
        bf16x8 r = R[w % 6];                      // consume before slot reuse
        // score s[w]: element (w>>4)*4+(w&3) in lanes with lg==(w>>2)&3
        float s = __shfl(sc[(w >> 4) * 4 + (w & 3)], ((w >> 2) & 3) * 16);
        if (w + 6 < WW) cissue(w + 6, (w + 6) % 6);
        asm volatile("" ::: "memory");
        bfx8_fma(cx, r, s);
    }

    const bool outmask = (n < node_sizes[b * CCC + c]) && (c < cross_lengths[b]);
    if (!outmask) {
        #pragma unroll
        for (int j = 0; j < 8; ++j) cx[j] = 0.0f;
    }
    float4* op = (float4*)(out + (size_t)t * DD + d0);
    op[0] = float4{cx[0], cx[1], cx[2], cx[3]};
    op[1] = float4{cx[4], cx[5], cx[6], cx[7]};
}

// ---------------- fp32 fallback (ws too small; not expected in practice) ----
__global__ __launch_bounds__(64) void prep_kernel(
    const float* __restrict__ con_hidden, const float* __restrict__ W_q,
    float* __restrict__ qout, float* __restrict__ hid_out)
{
    const int b = blockIdx.x;
    const int k = threadIdx.x;
    const float* h = con_hidden + b * DD;
    float acc = 0.0f;
    #pragma unroll 8
    for (int d = 0; d < DD; ++d) acc += h[d] * W_q[d * DKK + k];
    qout[b * DKK + k] = acc;
    const float4* src = (const float4*)h;
    float4* dst = (float4*)(hid_out + b * DD);
    for (int i = k; i < DD / 4; i += 64) dst[i] = src[i];
}

__global__ __launch_bounds__(64) void pack_wpre(
    const float* __restrict__ W_pre, bf16x8* __restrict__ wb)
{
    const int blk = blockIdx.x;
    const int ks = blk >> 2, nt = blk & 3;
    const int l  = threadIdx.x;
    const int lr = l & 15, lg = l >> 4;
    union { bf16x8 v; unsigned short s[8]; } u;
    #pragma unroll
    for (int j = 0; j < 8; ++j) {
        int k = ks * 32 + lg * 8 + j;
        u.s[j] = f2bf(W_pre[k * DKK + nt * 16 + lr]);
    }
    wb[blk * 64 + l] = u.v;
}

__global__ __launch_bounds__(256) void bag_kernel_f32(
    const int* __restrict__ token_ids, const int* __restrict__ node_lengths,
    const int* __restrict__ node_sizes, const int* __restrict__ cross_lengths,
    const float* __restrict__ embf, const float* __restrict__ b_pre,
    const float* __restrict__ v, const float* __restrict__ q,
    const bf16x8* __restrict__ wb, float* __restrict__ out)
{
    const int wid  = threadIdx.x >> 6;
    const int lane = threadIdx.x & 63;
    const int t = blockIdx.x * 4 + wid;
    const int b = t >> 7, cn = t & 127, c = cn >> 5, n = cn & 31;
    const int lr = lane & 15, lg = lane >> 4;

    const int L = node_lengths[t];
    const int* toks = token_ids + t * WW;
    int my_tok = 0;
    if (lane < 32 && lane < L) my_tok = toks[lane];
    const int tok0 = __shfl(my_tok, lr);
    const int tok1 = __shfl(my_tok, 16 + lr);
    const float* fp0 = embf + ((size_t)tok0 << 9) + lg * 8;
    const float* fp1 = embf + ((size_t)tok1 << 9) + lg * 8;

    f32x4 acc[2][4];
    #pragma unroll
    for (int mt = 0; mt < 2; ++mt)
        #pragma unroll
        for (int nt = 0; nt < 4; ++nt)
            acc[mt][nt] = (f32x4){0.f, 0.f, 0.f, 0.f};

    #pragma unroll 4
    for (int ks = 0; ks < 16; ++ks) {
        const float4* a0p = (const float4*)(fp0 + ks * 32);
        const float4* a1p = (const float4*)(fp1 + ks * 32);
        bf16x8 a0 = make_frag(a0p[0], a0p[1]);
        bf16x8 a1 = make_frag(a1p[0], a1p[1]);
        #pragma unroll
        for (int nt = 0; nt < 4; ++nt) {
            bf16x8 bb = wb[(ks * 4 + nt) * 64 + lane];
            acc[0][nt] = __builtin_amdgcn_mfma_f32_16x16x32_bf16(a0, bb, acc[0][nt], 0, 0, 0);
            acc[1][nt] = __builtin_amdgcn_mfma_f32_16x16x32_bf16(a1, bb, acc[1][nt], 0, 0, 0);
        }
    }

    float qb[4], vv[4];
    #pragma unroll
    for (int nt = 0; nt < 4; ++nt) {
        int cidx = nt * 16 + lr;
        qb[nt] = q[b * DKK + cidx] + b_pre[cidx];
        vv[nt] = v[cidx];
    }
    float ev[8];
    #pragma unroll
    for (int mt = 0; mt < 2; ++mt) {
        #pragma unroll
        for (int r = 0; r < 4; ++r) {
            float s = 0.0f;
            #pragma unroll
            for (int nt = 0; nt < 4; ++nt) {
                float pre = acc[mt][nt][r] + qb[nt];
                float ez = __expf(2.0f * pre);
                float th = 1.0f - 2.0f * __builtin_amdgcn_rcpf(ez + 1.0f);
                s += th * vv[nt];
            }
            s += __shfl_xor(s, 1); s += __shfl_xor(s, 2);
            s += __shfl_xor(s, 4); s += __shfl_xor(s, 8);
            ev[mt * 4 + r] = s;
        }
    }
    float mx = ev[0];
    #pragma unroll
    for (int j = 1; j < 8; ++j) mx = fmaxf(mx, ev[j]);
    mx = fmaxf(mx, __shfl_xor(mx, 16));
    mx = fmaxf(mx, __shfl_xor(mx, 32));
    float sc[8], sm = 0.0f;
    #pragma unroll
    for (int j = 0; j < 8; ++j) { sc[j] = __expf(ev[j] - mx); sm += sc[j]; }
    sm += __shfl_xor(sm, 16); sm += __shfl_xor(sm, 32);
    const float inv = 1.0f / sm;
    #pragma unroll
    for (int j = 0; j < 8; ++j) sc[j] *= inv;

    const int d0 = lane * 8;
    float cx[8];
    #pragma unroll
    for (int j = 0; j < 8; ++j) cx[j] = 0.0f;
    #pragma unroll
    for (int w = 0; w < WW; ++w) {
        int tk = __shfl(my_tok, w);
        float s = __shfl(sc[(w >> 4) * 4 + (w & 3)], ((w >> 2) & 3) * 16);
        const float4* pr = (const float4*)(embf + ((size_t)tk << 9) + d0);
        float4 x0 = pr[0], x1 = pr[1];
        cx[0] += s * x0.x; cx[1] += s * x0.y; cx[2] += s * x0.z; cx[3] += s * x0.w;
        cx[4] += s * x1.x; cx[5] += s * x1.y; cx[6] += s * x1.z; cx[7] += s * x1.w;
    }
    const bool outmask = (n < node_sizes[b * CCC + c]) && (c < cross_lengths[b]);
    if (!outmask) {
        #pragma unroll
        for (int j = 0; j < 8; ++j) cx[j] = 0.0f;
    }
    float4* op = (float4*)(out + (size_t)t * DD + d0);
    op[0] = float4{cx[0], cx[1], cx[2], cx[3]};
    op[1] = float4{cx[4], cx[5], cx[6], cx[7]};
}

extern "C" void kernel_launch(void* const* d_in, const int* in_sizes, int n_in,
                              void* d_out, int out_size, void* d_ws, size_t ws_size,
                              hipStream_t stream) {
    const int*   token_ids     = (const int*)d_in[0];
    const int*   node_lengths  = (const int*)d_in[1];
    const int*   node_sizes    = (const int*)d_in[2];
    const int*   cross_lengths = (const int*)d_in[3];
    const float* con_hidden    = (const float*)d_in[4];
    const float* emb           = (const float*)d_in[5];
    const float* W_pre         = (const float*)d_in[6];
    const float* b_pre         = (const float*)d_in[7];
    const float* W_q           = (const float*)d_in[8];
    const float* v             = (const float*)d_in[9];

    float*  out     = (float*)d_out;
    float*  hid_out = out + (size_t)TB * DD;                 // second output
    float*  q       = (float*)d_ws;                          // 16 KB
    bf16x8* wb      = (bf16x8*)((char*)d_ws + 16 * 1024);    // 64 KB packed W_pre
    unsigned short* embh = (unsigned short*)((char*)d_ws + 80 * 1024);  // 32 MB

    const size_t need = 80 * 1024 + (size_t)32000 * DD * 2;

    if (ws_size >= need) {
        preproc_kernel<<<CONV_BLKS + 128, 256, 0, stream>>>(
            emb, embh, con_hidden, W_q, q, hid_out, W_pre, wb);
        bag_kernel<<<TB / 8, 512, 0, stream>>>(
            token_ids, node_lengths, node_sizes, cross_lengths,
            embh, b_pre, v, q, wb, out);
    } else {
        prep_kernel<<<64, 64, 0, stream>>>(con_hidden, W_q, q, hid_out);
        pack_wpre<<<64, 64, 0, stream>>>(W_pre, wb);
        bag_kernel_f32<<<TB / 4, 256, 0, stream>>>(
            token_ids, node_lengths, node_sizes, cross_lengths,
            emb, b_pre, v, q, wb, out);
    }
}

// Round 10
// 93.402 us; speedup vs baseline: 1.0225x; 1.0225x over previous
//
#include <hip/hip_runtime.h>
#include <hip/hip_bf16.h>

#define TB   8192   // B*C*N bags
#define WW   32     // words per bag
#define DD   512    // d_model
#define DKK  64     // attention dim
#define CCC  4      // max cross

#define CONV_BLKS   2000
#define CONV_CHUNKS 2048000   // 32000*512/8

using bf16x8 = __attribute__((ext_vector_type(8))) short;
using f32x4  = __attribute__((ext_vector_type(4))) float;

__device__ __forceinline__ unsigned short f2bf(float x) {
    union { float f; unsigned u; } u;
    u.f = x;
    unsigned r = u.u + 0x7fffu + ((u.u >> 16) & 1u);
    return (unsigned short)(r >> 16);
}

__device__ __forceinline__ bf16x8 make_frag(float4 x, float4 y) {
    union { bf16x8 v; unsigned short s[8]; } u;
    u.s[0] = f2bf(x.x); u.s[1] = f2bf(x.y); u.s[2] = f2bf(x.z); u.s[3] = f2bf(x.w);
    u.s[4] = f2bf(y.x); u.s[5] = f2bf(y.y); u.s[6] = f2bf(y.z); u.s[7] = f2bf(y.w);
    return u.v;
}

// fma 8 bf16 elems (packed) into fp32 accumulators: cx[j] += s * elem[j]
__device__ __forceinline__ void bfx8_fma(float* cx, bf16x8 r, float s) {
    union { bf16x8 v; unsigned u[4]; } u; u.v = r;
    #pragma unroll
    for (int j = 0; j < 4; ++j) {
        float lo = __uint_as_float(u.u[j] << 16);
        float hi = __uint_as_float(u.u[j] & 0xffff0000u);
        cx[2 * j]     += s * lo;
        cx[2 * j + 1] += s * hi;
    }
}

// ---------------- fused preprocessing ----------------
// blocks [0, CONV_BLKS)       : emb fp32 -> bf16 (grid-stride, 4 chunks/thread)
// blocks [CONV_BLKS, +64)     : prep (q GEMV + hidden copy)
// blocks [CONV_BLKS+64, +128) : pack W_pre fragments
__global__ __launch_bounds__(256) void preproc_kernel(
    const float* __restrict__ emb,
    unsigned short* __restrict__ embh,
    const float* __restrict__ con_hidden,  // [64][512]
    const float* __restrict__ W_q,         // [512][64]
    float* __restrict__ qout,              // [64][64]
    float* __restrict__ hid_out,           // [64][512]
    const float* __restrict__ W_pre,       // [512][64]
    bf16x8* __restrict__ wb)               // 64 frags * 64 lanes
{
    const int blk = blockIdx.x;
    const int tid = threadIdx.x;
    if (blk < CONV_BLKS) {
        // 2048000 chunks / (2000*256 threads) = exactly 4 per thread
        size_t idx = (size_t)blk * 256 + tid;
        #pragma unroll 4
        for (int it = 0; it < 4; ++it) {
            const size_t i = idx * 8;
            const float4* p = (const float4*)(emb + i);
            float4 a = p[0], b = p[1];
            *(bf16x8*)(embh + i) = make_frag(a, b);
            idx += (size_t)CONV_BLKS * 256;
        }
    } else if (blk < CONV_BLKS + 64) {
        if (tid >= 64) return;
        const int b = blk - CONV_BLKS;
        const int k = tid;
        const float* h = con_hidden + b * DD;
        float acc = 0.0f;
        #pragma unroll 8
        for (int d = 0; d < DD; ++d) acc += h[d] * W_q[d * DKK + k];
        qout[b * DKK + k] = acc;
        const float4* src = (const float4*)h;
        float4* dst = (float4*)(hid_out + b * DD);
        for (int i = k; i < DD / 4; i += 64) dst[i] = src[i];
    } else {
        if (tid >= 64) return;
        const int fb = blk - CONV_BLKS - 64;   // ks*4 + nt
        const int ks = fb >> 2, nt = fb & 3;
        const int lr = tid & 15, lg = tid >> 4;
        union { bf16x8 v; unsigned short s[8]; } u;
        #pragma unroll
        for (int j = 0; j < 8; ++j) {
            int k = ks * 32 + lg * 8 + j;
            u.s[j] = f2bf(W_pre[k * DKK + nt * 16 + lr]);
        }
        wb[fb * 64 + tid] = u.v;
    }
}

// ---------------- main bag kernel: 8 waves/block, wb in LDS ----------------
// NOTE: plain launch_bounds(512). Round-8's (512,4) clamped VGPR to 64 and
// spilled the 8-deep pipeline to scratch (+44 MB WRITE_SIZE). LDS (64 KB)
// already caps occupancy at 2 blocks/CU = 4 waves/SIMD, which permits 128
// VGPR — let the allocator use it.
__global__ __launch_bounds__(512) void bag_kernel(
    const int* __restrict__ token_ids,     // [8192][32]
    const int* __restrict__ node_lengths,  // [8192]
    const int* __restrict__ node_sizes,    // [256]
    const int* __restrict__ cross_lengths, // [64]
    const unsigned short* __restrict__ embh, // [32000][512] bf16, row 0 zeros
    const float* __restrict__ b_pre,       // [64]
    const float* __restrict__ v,           // [64]
    const float* __restrict__ q,           // [64][64]
    const bf16x8* __restrict__ wb,         // packed W_pre fragments (64 KB)
    float* __restrict__ out)               // [8192][512]
{
    const int tid  = threadIdx.x;
    const int wid  = tid >> 6;
    const int lane = tid & 63;
    const int t = blockIdx.x * 8 + wid;
    const int b = t >> 7, cn = t & 127, c = cn >> 5, n = cn & 31;
    const int lr = lane & 15, lg = lane >> 4;

    __shared__ bf16x8 swb[4096];   // 64 KB shared W_pre fragments

    const int L = node_lengths[t];
    const int* toks = token_ids + t * WW;

    // lane w (<32) holds masked token id of word w (emb row 0 is all-zero)
    int my_tok = 0;
    if (lane < 32 && lane < L) my_tok = toks[lane];

    // A-row pointers for the two M-tiles (words lr and 16+lr)
    const int tok0 = __shfl(my_tok, lr);
    const int tok1 = __shfl(my_tok, 16 + lr);
    const unsigned short* hp0 = embh + ((size_t)tok0 << 9) + lg * 8;
    const unsigned short* hp1 = embh + ((size_t)tok1 << 9) + lg * 8;

    bf16x8 A0[8], A1[8], Bs[2][4];
    auto loadA = [&](int ks, int sl) {
        A0[sl] = *(const bf16x8*)(hp0 + ks * 32);
        A1[sl] = *(const bf16x8*)(hp1 + ks * 32);
    };
    auto loadB = [&](int ks, int sl) {
        #pragma unroll
        for (int nt = 0; nt < 4; ++nt)
            Bs[sl][nt] = swb[(ks * 4 + nt) * 64 + lane];
    };

    // 8-deep gather prologue BEFORE the LDS fill so it hides under the fill
    loadA(0, 0); loadA(1, 1); loadA(2, 2); loadA(3, 3);
    loadA(4, 4); loadA(5, 5); loadA(6, 6); loadA(7, 7);
    asm volatile("" ::: "memory");

    // cooperative fill of wb -> LDS (4096 x 16B, 8 iters/thread)
    #pragma unroll
    for (int i = tid; i < 4096; i += 512) swb[i] = wb[i];
    __syncthreads();            // the ONLY block-wide barrier

    f32x4 acc[2][4];
    #pragma unroll
    for (int mt = 0; mt < 2; ++mt)
        #pragma unroll
        for (int nt = 0; nt < 4; ++nt)
            acc[mt][nt] = (f32x4){0.f, 0.f, 0.f, 0.f};

    loadB(0, 0);
    asm volatile("" ::: "memory");

    // ---- pre = bag @ W_pre via MFMA: A 8-deep (global), B 2-deep (LDS) ----
    #pragma unroll
    for (int ks = 0; ks < 16; ++ks) {
        bf16x8 a0 = A0[ks & 7], a1 = A1[ks & 7];   // consume before slot reuse
        if (ks + 8 < 16) loadA(ks + 8, ks & 7);
        if (ks + 1 < 16) loadB(ks + 1, (ks + 1) & 1);
        asm volatile("" ::: "memory");             // loads cannot sink past here
        const int bs = ks & 1;
        acc[0][0] = __builtin_amdgcn_mfma_f32_16x16x32_bf16(a0, Bs[bs][0], acc[0][0], 0, 0, 0);
        acc[0][1] = __builtin_amdgcn_mfma_f32_16x16x32_bf16(a0, Bs[bs][1], acc[0][1], 0, 0, 0);
        acc[0][2] = __builtin_amdgcn_mfma_f32_16x16x32_bf16(a0, Bs[bs][2], acc[0][2], 0, 0, 0);
        acc[0][3] = __builtin_amdgcn_mfma_f32_16x16x32_bf16(a0, Bs[bs][3], acc[0][3], 0, 0, 0);
        acc[1][0] = __builtin_amdgcn_mfma_f32_16x16x32_bf16(a1, Bs[bs][0], acc[1][0], 0, 0, 0);
        acc[1][1] = __builtin_amdgcn_mfma_f32_16x16x32_bf16(a1, Bs[bs][1], acc[1][1], 0, 0, 0);
        acc[1][2] = __builtin_amdgcn_mfma_f32_16x16x32_bf16(a1, Bs[bs][2], acc[1][2], 0, 0, 0);
        acc[1][3] = __builtin_amdgcn_mfma_f32_16x16x32_bf16(a1, Bs[bs][3], acc[1][3], 0, 0, 0);
    }

    // ---- kick off context-row prefetch NOW: addresses don't need scores ----
    const int d0 = lane * 8;
    bf16x8 R[6];
    auto cissue = [&](int w, int sl) {
        int tk = __shfl(my_tok, w);
        R[sl] = *(const bf16x8*)(embh + ((size_t)tk << 9) + d0);
    };
    cissue(0, 0); cissue(1, 1); cissue(2, 2);
    cissue(3, 3); cissue(4, 4); cissue(5, 5);
    asm volatile("" ::: "memory");   // in flight across energy+softmax

    // ---- energy: e[w] = sum_k tanh(pre + b_pre + q) * v  (all in registers) ----
    // C layout: col = nt*16 + lr ; row(word) = mt*16 + lg*4 + r
    float qb[4], vv[4];
    #pragma unroll
    for (int nt = 0; nt < 4; ++nt) {
        int cidx = nt * 16 + lr;
        qb[nt] = q[b * DKK + cidx] + b_pre[cidx];
        vv[nt] = v[cidx];
    }
    float ev[8];   // ev[mt*4+r] = e[mt*16 + lg*4 + r], replicated across lr
    #pragma unroll
    for (int mt = 0; mt < 2; ++mt) {
        #pragma unroll
        for (int r = 0; r < 4; ++r) {
            float s = 0.0f;
            #pragma unroll
            for (int nt = 0; nt < 4; ++nt) {
                float pre = acc[mt][nt][r] + qb[nt];
                float ez = __expf(2.0f * pre);                 // tanh via exp
                float th = 1.0f - 2.0f * __builtin_amdgcn_rcpf(ez + 1.0f);
                s += th * vv[nt];
            }
            s += __shfl_xor(s, 1);
            s += __shfl_xor(s, 2);
            s += __shfl_xor(s, 4);
            s += __shfl_xor(s, 8);   // every lane in the lg-group has e[w]
            ev[mt * 4 + r] = s;
        }
    }

    // ---- softmax over 32 word slots, wave-local ----
    float mx = ev[0];
    #pragma unroll
    for (int j = 1; j < 8; ++j) mx = fmaxf(mx, ev[j]);
    mx = fmaxf(mx, __shfl_xor(mx, 16));
    mx = fmaxf(mx, __shfl_xor(mx, 32));
    float sc[8], sm = 0.0f;
    #pragma unroll
    for (int j = 0; j < 8; ++j) { sc[j] = __expf(ev[j] - mx); sm += sc[j]; }
    sm += __shfl_xor(sm, 16);
    sm += __shfl_xor(sm, 32);
    const float inv = 1.0f / sm;
    #pragma unroll
    for (int j = 0; j < 8; ++j) sc[j] *= inv;

    // ---- context: lane owns 8 consecutive d's; 6-deep pipelined gather ----
    float cx[8];
    #pragma unroll
    for (int j = 0; j < 8; ++j) cx[j] = 0.0f;

    #pragma unroll
    for (int w = 0; w < WW; ++w) {
        bf16x8 r = R[w % 6];                      // consume before slot reuse
        // score s[w]: element (w>>4)*4+(w&3) in lanes with lg==(w>>2)&3
        float s = __shfl(sc[(w >> 4) * 4 + (w & 3)], ((w >> 2) & 3) * 16);
        if (w + 6 < WW) cissue(w + 6, (w + 6) % 6);
        asm volatile("" ::: "memory");
        bfx8_fma(cx, r, s);
    }

    const bool outmask = (n < node_sizes[b * CCC + c]) && (c < cross_lengths[b]);
    if (!outmask) {
        #pragma unroll
        for (int j = 0; j < 8; ++j) cx[j] = 0.0f;
    }
    float4* op = (float4*)(out + (size_t)t * DD + d0);
    op[0] = float4{cx[0], cx[1], cx[2], cx[3]};
    op[1] = float4{cx[4], cx[5], cx[6], cx[7]};
}

// ---------------- fp32 fallback (ws too small; not expected in practice) ----
__global__ __launch_bounds__(64) void prep_kernel(
    const float* __restrict__ con_hidden, const float* __restrict__ W_q,
    float* __restrict__ qout, float* __restrict__ hid_out)
{
    const int b = blockIdx.x;
    const int k = threadIdx.x;
    const float* h = con_hidden + b * DD;
    float acc = 0.0f;
    #pragma unroll 8
    for (int d = 0; d < DD; ++d) acc += h[d] * W_q[d * DKK + k];
    qout[b * DKK + k] = acc;
    const float4* src = (const float4*)h;
    float4* dst = (float4*)(hid_out + b * DD);
    for (int i = k; i < DD / 4; i += 64) dst[i] = src[i];
}

__global__ __launch_bounds__(64) void pack_wpre(
    const float* __restrict__ W_pre, bf16x8* __restrict__ wb)
{
    const int blk = blockIdx.x;
    const int ks = blk >> 2, nt = blk & 3;
    const int l  = threadIdx.x;
    const int lr = l & 15, lg = l >> 4;
    union { bf16x8 v; unsigned short s[8]; } u;
    #pragma unroll
    for (int j = 0; j < 8; ++j) {
        int k = ks * 32 + lg * 8 + j;
        u.s[j] = f2bf(W_pre[k * DKK + nt * 16 + lr]);
    }
    wb[blk * 64 + l] = u.v;
}

__global__ __launch_bounds__(256) void bag_kernel_f32(
    const int* __restrict__ token_ids, const int* __restrict__ node_lengths,
    const int* __restrict__ node_sizes, const int* __restrict__ cross_lengths,
    const float* __restrict__ embf, const float* __restrict__ b_pre,
    const float* __restrict__ v, const float* __restrict__ q,
    const bf16x8* __restrict__ wb, float* __restrict__ out)
{
    const int wid  = threadIdx.x >> 6;
    const int lane = threadIdx.x & 63;
    const int t = blockIdx.x * 4 + wid;
    const int b = t >> 7, cn = t & 127, c = cn >> 5, n = cn & 31;
    const int lr = lane & 15, lg = lane >> 4;

    const int L = node_lengths[t];
    const int* toks = token_ids + t * WW;
    int my_tok = 0;
    if (lane < 32 && lane < L) my_tok = toks[lane];
    const int tok0 = __shfl(my_tok, lr);
    const int tok1 = __shfl(my_tok, 16 + lr);
    const float* fp0 = embf + ((size_t)tok0 << 9) + lg * 8;
    const float* fp1 = embf + ((size_t)tok1 << 9) + lg * 8;

    f32x4 acc[2][4];
    #pragma unroll
    for (int mt = 0; mt < 2; ++mt)
        #pragma unroll
        for (int nt = 0; nt < 4; ++nt)
            acc[mt][nt] = (f32x4){0.f, 0.f, 0.f, 0.f};

    #pragma unroll 4
    for (int ks = 0; ks < 16; ++ks) {
        const float4* a0p = (const float4*)(fp0 + ks * 32);
        const float4* a1p = (const float4*)(fp1 + ks * 32);
        bf16x8 a0 = make_frag(a0p[0], a0p[1]);
        bf16x8 a1 = make_frag(a1p[0], a1p[1]);
        #pragma unroll
        for (int nt = 0; nt < 4; ++nt) {
            bf16x8 bb = wb[(ks * 4 + nt) * 64 + lane];
            acc[0][nt] = __builtin_amdgcn_mfma_f32_16x16x32_bf16(a0, bb, acc[0][nt], 0, 0, 0);
            acc[1][nt] = __builtin_amdgcn_mfma_f32_16x16x32_bf16(a1, bb, acc[1][nt], 0, 0, 0);
        }
    }

    float qb[4], vv[4];
    #pragma unroll
    for (int nt = 0; nt < 4; ++nt) {
        int cidx = nt * 16 + lr;
        qb[nt] = q[b * DKK + cidx] + b_pre[cidx];
        vv[nt] = v[cidx];
    }
    float ev[8];
    #pragma unroll
    for (int mt = 0; mt < 2; ++mt) {
        #pragma unroll
        for (int r = 0; r < 4; ++r) {
            float s = 0.0f;
            #pragma unroll
            for (int nt = 0; nt < 4; ++nt) {
                float pre = acc[mt][nt][r] + qb[nt];
                float ez = __expf(2.0f * pre);
                float th = 1.0f - 2.0f * __builtin_amdgcn_rcpf(ez + 1.0f);
                s += th * vv[nt];
            }
            s += __shfl_xor(s, 1); s += __shfl_xor(s, 2);
            s += __shfl_xor(s, 4); s += __shfl_xor(s, 8);
            ev[mt * 4 + r] = s;
        }
    }
    float mx = ev[0];
    #pragma unroll
    for (int j = 1; j < 8; ++j) mx = fmaxf(mx, ev[j]);
    mx = fmaxf(mx, __shfl_xor(mx, 16));
    mx = fmaxf(mx, __shfl_xor(mx, 32));
    float sc[8], sm = 0.0f;
    #pragma unroll
    for (int j = 0; j < 8; ++j) { sc[j] = __expf(ev[j] - mx); sm += sc[j]; }
    sm += __shfl_xor(sm, 16); sm += __shfl_xor(sm, 32);
    const float inv = 1.0f / sm;
    #pragma unroll
    for (int j = 0; j < 8; ++j) sc[j] *= inv;

    const int d0 = lane * 8;
    float cx[8];
    #pragma unroll
    for (int j = 0; j < 8; ++j) cx[j] = 0.0f;
    #pragma unroll
    for (int w = 0; w < WW; ++w) {
        int tk = __shfl(my_tok, w);
        float s = __shfl(sc[(w >> 4) * 4 + (w & 3)], ((w >> 2) & 3) * 16);
        const float4* pr = (const float4*)(embf + ((size_t)tk << 9) + d0);
        float4 x0 = pr[0], x1 = pr[1];
        cx[0] += s * x0.x; cx[1] += s * x0.y; cx[2] += s * x0.z; cx[3] += s * x0.w;
        cx[4] += s * x1.x; cx[5] += s * x1.y; cx[6] += s * x1.z; cx[7] += s * x1.w;
    }
    const bool outmask = (n < node_sizes[b * CCC + c]) && (c < cross_lengths[b]);
    if (!outmask) {
        #pragma unroll
        for (int j = 0; j < 8; ++j) cx[j] = 0.0f;
    }
    float4* op = (float4*)(out + (size_t)t * DD + d0);
    op[0] = float4{cx[0], cx[1], cx[2], cx[3]};
    op[1] = float4{cx[4], cx[5], cx[6], cx[7]};
}

extern "C" void kernel_launch(void* const* d_in, const int* in_sizes, int n_in,
                              void* d_out, int out_size, void* d_ws, size_t ws_size,
                              hipStream_t stream) {
    const int*   token_ids     = (const int*)d_in[0];
    const int*   node_lengths  = (const int*)d_in[1];
    const int*   node_sizes    = (const int*)d_in[2];
    const int*   cross_lengths = (const int*)d_in[3];
    const float* con_hidden    = (const float*)d_in[4];
    const float* emb           = (const float*)d_in[5];
    const float* W_pre         = (const float*)d_in[6];
    const float* b_pre         = (const float*)d_in[7];
    const float* W_q           = (const float*)d_in[8];
    const float* v             = (const float*)d_in[9];

    float*  out     = (float*)d_out;
    float*  hid_out = out + (size_t)TB * DD;                 // second output
    float*  q       = (float*)d_ws;                          // 16 KB
    bf16x8* wb      = (bf16x8*)((char*)d_ws + 16 * 1024);    // 64 KB packed W_pre
    unsigned short* embh = (unsigned short*)((char*)d_ws + 80 * 1024);  // 32 MB

    const size_t need = 80 * 1024 + (size_t)32000 * DD * 2;

    if (ws_size >= need) {
        preproc_kernel<<<CONV_BLKS + 128, 256, 0, stream>>>(
            emb, embh, con_hidden, W_q, q, hid_out, W_pre, wb);
        bag_kernel<<<TB / 8, 512, 0, stream>>>(
            token_ids, node_lengths, node_sizes, cross_lengths,
            embh, b_pre, v, q, wb, out);
    } else {
        prep_kernel<<<64, 64, 0, stream>>>(con_hidden, W_q, q, hid_out);
        pack_wpre<<<64, 64, 0, stream>>>(W_pre, wb);
        bag_kernel_f32<<<TB / 4, 256, 0, stream>>>(
            token_ids, node_lengths, node_sizes, cross_lengths,
            emb, b_pre, v, q, wb, out);
    }
}

// Round 11
// 74.260 us; speedup vs baseline: 1.2861x; 1.2578x over previous
//
#include <hip/hip_runtime.h>
#include <hip/hip_bf16.h>

#define TB   8192   // B*C*N bags
#define WW   32     // words per bag
#define DD   512    // d_model
#define DKK  64     // attention dim
#define CCC  4      // max cross

#define CONV_BLKS   2000

using bf16x8 = __attribute__((ext_vector_type(8))) short;
using f32x4  = __attribute__((ext_vector_type(4))) float;
using f32x2  = __attribute__((ext_vector_type(2))) float;

__device__ __forceinline__ unsigned short f2bf(float x) {
    union { float f; unsigned u; } u;
    u.f = x;
    unsigned r = u.u + 0x7fffu + ((u.u >> 16) & 1u);
    return (unsigned short)(r >> 16);
}

__device__ __forceinline__ bf16x8 make_frag(float4 x, float4 y) {
    union { bf16x8 v; unsigned short s[8]; } u;
    u.s[0] = f2bf(x.x); u.s[1] = f2bf(x.y); u.s[2] = f2bf(x.z); u.s[3] = f2bf(x.w);
    u.s[4] = f2bf(y.x); u.s[5] = f2bf(y.y); u.s[6] = f2bf(y.z); u.s[7] = f2bf(y.w);
    return u.v;
}

// pack 8 fp32 -> 8 fp8 e4m3 (HW cvt, RNE) as uint2; byte j == element j
__device__ __forceinline__ uint2 pack_fp8x8(float4 a, float4 b) {
    int lo = 0, hi = 0;
    lo = __builtin_amdgcn_cvt_pk_fp8_f32(a.x, a.y, lo, false);
    lo = __builtin_amdgcn_cvt_pk_fp8_f32(a.z, a.w, lo, true);
    hi = __builtin_amdgcn_cvt_pk_fp8_f32(b.x, b.y, hi, false);
    hi = __builtin_amdgcn_cvt_pk_fp8_f32(b.z, b.w, hi, true);
    uint2 r; r.x = (unsigned)lo; r.y = (unsigned)hi;
    return r;
}

__device__ __forceinline__ long long u2l(uint2 u) {
    union { uint2 v; long long l; } c; c.v = u; return c.l;
}

// fma 8 fp8 elems into fp32 accumulators: cx[j] += s * elem[j]
__device__ __forceinline__ void fp8x8_fma(float* cx, uint2 r, float s) {
    f32x2 f01 = __builtin_amdgcn_cvt_pk_f32_fp8((int)r.x, false);
    f32x2 f23 = __builtin_amdgcn_cvt_pk_f32_fp8((int)r.x, true);
    f32x2 f45 = __builtin_amdgcn_cvt_pk_f32_fp8((int)r.y, false);
    f32x2 f67 = __builtin_amdgcn_cvt_pk_f32_fp8((int)r.y, true);
    cx[0] += s * f01[0]; cx[1] += s * f01[1];
    cx[2] += s * f23[0]; cx[3] += s * f23[1];
    cx[4] += s * f45[0]; cx[5] += s * f45[1];
    cx[6] += s * f67[0]; cx[7] += s * f67[1];
}

// ---------------- fused preprocessing ----------------
// blocks [0, CONV_BLKS)       : emb fp32 -> fp8 (grid-stride, 4 chunks/thread)
// blocks [CONV_BLKS, +64)     : prep (q GEMV + hidden copy)
// blocks [CONV_BLKS+64, +128) : pack W_pre fp8 fragments
__global__ __launch_bounds__(256) void preproc_kernel(
    const float* __restrict__ emb,
    unsigned char* __restrict__ emb8,      // [32000*512] fp8
    const float* __restrict__ con_hidden,  // [64][512]
    const float* __restrict__ W_q,         // [512][64]
    float* __restrict__ qout,              // [64][64]
    float* __restrict__ hid_out,           // [64][512]
    const float* __restrict__ W_pre,       // [512][64]
    uint2* __restrict__ wb8)               // 64 frags * 64 lanes * 8B = 32 KB
{
    const int blk = blockIdx.x;
    const int tid = threadIdx.x;
    if (blk < CONV_BLKS) {
        size_t idx = (size_t)blk * 256 + tid;   // 4 chunks of 8 elems each
        #pragma unroll 4
        for (int it = 0; it < 4; ++it) {
            const size_t i = idx * 8;
            const float4* p = (const float4*)(emb + i);
            float4 a = p[0], b = p[1];
            *(uint2*)(emb8 + i) = pack_fp8x8(a, b);
            idx += (size_t)CONV_BLKS * 256;
        }
    } else if (blk < CONV_BLKS + 64) {
        if (tid >= 64) return;
        const int b = blk - CONV_BLKS;
        const int k = tid;
        const float* h = con_hidden + b * DD;
        float acc = 0.0f;
        #pragma unroll 8
        for (int d = 0; d < DD; ++d) acc += h[d] * W_q[d * DKK + k];
        qout[b * DKK + k] = acc;
        const float4* src = (const float4*)h;
        float4* dst = (float4*)(hid_out + b * DD);
        for (int i = k; i < DD / 4; i += 64) dst[i] = src[i];
    } else {
        if (tid >= 64) return;
        const int fb = blk - CONV_BLKS - 64;   // ks*4 + nt
        const int ks = fb >> 2, nt = fb & 3;
        const int lr = tid & 15, lg = tid >> 4;
        float w[8];
        #pragma unroll
        for (int j = 0; j < 8; ++j)
            w[j] = W_pre[(ks * 32 + lg * 8 + j) * DKK + nt * 16 + lr];
        wb8[fb * 64 + tid] = pack_fp8x8(float4{w[0], w[1], w[2], w[3]},
                                        float4{w[4], w[5], w[6], w[7]});
    }
}

// ---------------- main bag kernel: 8 waves/block, fp8 everywhere ----------------
__global__ __launch_bounds__(512) void bag_kernel(
    const int* __restrict__ token_ids,     // [8192][32]
    const int* __restrict__ node_lengths,  // [8192]
    const int* __restrict__ node_sizes,    // [256]
    const int* __restrict__ cross_lengths, // [64]
    const unsigned char* __restrict__ emb8, // [32000*512] fp8, row 0 zeros
    const float* __restrict__ b_pre,       // [64]
    const float* __restrict__ v,           // [64]
    const float* __restrict__ q,           // [64][64]
    const uint2* __restrict__ wb8,         // packed W_pre fp8 fragments (32 KB)
    float* __restrict__ out)               // [8192][512]
{
    const int tid  = threadIdx.x;
    const int wid  = tid >> 6;
    const int lane = tid & 63;
    const int t = blockIdx.x * 8 + wid;
    const int b = t >> 7, cn = t & 127, c = cn >> 5, n = cn & 31;
    const int lr = lane & 15, lg = lane >> 4;

    __shared__ uint2 swb[4096];   // 32 KB shared W_pre fp8 fragments

    const int L = node_lengths[t];
    const int* toks = token_ids + t * WW;

    // lane w (<32) holds masked token id of word w (emb row 0 is all-zero)
    int my_tok = 0;
    if (lane < 32 && lane < L) my_tok = toks[lane];

    // A-row byte pointers for the two M-tiles (words lr and 16+lr)
    const int tok0 = __shfl(my_tok, lr);
    const int tok1 = __shfl(my_tok, 16 + lr);
    const unsigned char* hp0 = emb8 + ((size_t)tok0 << 9) + lg * 8;
    const unsigned char* hp1 = emb8 + ((size_t)tok1 << 9) + lg * 8;

    uint2 A0[8], A1[8], Bs[2][4];
    auto loadA = [&](int ks, int sl) {
        A0[sl] = *(const uint2*)(hp0 + ks * 32);
        A1[sl] = *(const uint2*)(hp1 + ks * 32);
    };
    auto loadB = [&](int ks, int sl) {
        #pragma unroll
        for (int nt = 0; nt < 4; ++nt)
            Bs[sl][nt] = swb[(ks * 4 + nt) * 64 + lane];
    };

    // 8-deep gather prologue BEFORE the LDS fill so it hides under the fill
    loadA(0, 0); loadA(1, 1); loadA(2, 2); loadA(3, 3);
    loadA(4, 4); loadA(5, 5); loadA(6, 6); loadA(7, 7);
    asm volatile("" ::: "memory");

    // cooperative fill of wb8 -> LDS (4096 x 8B, 8 iters/thread)
    #pragma unroll
    for (int i = tid; i < 4096; i += 512) swb[i] = wb8[i];
    __syncthreads();            // the ONLY block-wide barrier

    f32x4 acc[2][4];
    #pragma unroll
    for (int mt = 0; mt < 2; ++mt)
        #pragma unroll
        for (int nt = 0; nt < 4; ++nt)
            acc[mt][nt] = (f32x4){0.f, 0.f, 0.f, 0.f};

    loadB(0, 0);
    asm volatile("" ::: "memory");

    // ---- pre = bag @ W_pre via fp8 MFMA: A 8-deep (global), B 2-deep (LDS) ----
    #pragma unroll
    for (int ks = 0; ks < 16; ++ks) {
        long long a0 = u2l(A0[ks & 7]), a1 = u2l(A1[ks & 7]);
        if (ks + 8 < 16) loadA(ks + 8, ks & 7);
        if (ks + 1 < 16) loadB(ks + 1, (ks + 1) & 1);
        asm volatile("" ::: "memory");
        const int bs = ks & 1;
        long long b0 = u2l(Bs[bs][0]), b1 = u2l(Bs[bs][1]);
        long long b2 = u2l(Bs[bs][2]), b3 = u2l(Bs[bs][3]);
        acc[0][0] = __builtin_amdgcn_mfma_f32_16x16x32_fp8_fp8(a0, b0, acc[0][0], 0, 0, 0);
        acc[0][1] = __builtin_amdgcn_mfma_f32_16x16x32_fp8_fp8(a0, b1, acc[0][1], 0, 0, 0);
        acc[0][2] = __builtin_amdgcn_mfma_f32_16x16x32_fp8_fp8(a0, b2, acc[0][2], 0, 0, 0);
        acc[0][3] = __builtin_amdgcn_mfma_f32_16x16x32_fp8_fp8(a0, b3, acc[0][3], 0, 0, 0);
        acc[1][0] = __builtin_amdgcn_mfma_f32_16x16x32_fp8_fp8(a1, b0, acc[1][0], 0, 0, 0);
        acc[1][1] = __builtin_amdgcn_mfma_f32_16x16x32_fp8_fp8(a1, b1, acc[1][1], 0, 0, 0);
        acc[1][2] = __builtin_amdgcn_mfma_f32_16x16x32_fp8_fp8(a1, b2, acc[1][2], 0, 0, 0);
        acc[1][3] = __builtin_amdgcn_mfma_f32_16x16x32_fp8_fp8(a1, b3, acc[1][3], 0, 0, 0);
    }

    // ---- kick off context-row prefetch NOW: addresses don't need scores ----
    const int d0 = lane * 8;
    uint2 R[6];
    auto cissue = [&](int w, int sl) {
        int tk = __shfl(my_tok, w);
        R[sl] = *(const uint2*)(emb8 + ((size_t)tk << 9) + d0);
    };
    cissue(0, 0); cissue(1, 1); cissue(2, 2);
    cissue(3, 3); cissue(4, 4); cissue(5, 5);
    asm volatile("" ::: "memory");   // in flight across energy+softmax

    // ---- energy: e[w] = sum_k tanh(pre + b_pre + q) * v  (all in registers) ----
    // C layout: col = nt*16 + lr ; row(word) = mt*16 + lg*4 + r
    float qb[4], vv[4];
    #pragma unroll
    for (int nt = 0; nt < 4; ++nt) {
        int cidx = nt * 16 + lr;
        qb[nt] = q[b * DKK + cidx] + b_pre[cidx];
        vv[nt] = v[cidx];
    }
    float ev[8];   // ev[mt*4+r] = e[mt*16 + lg*4 + r], replicated across lr
    #pragma unroll
    for (int mt = 0; mt < 2; ++mt) {
        #pragma unroll
        for (int r = 0; r < 4; ++r) {
            float s = 0.0f;
            #pragma unroll
            for (int nt = 0; nt < 4; ++nt) {
                float pre = acc[mt][nt][r] + qb[nt];
                float ez = __expf(2.0f * pre);                 // tanh via exp
                float th = 1.0f - 2.0f * __builtin_amdgcn_rcpf(ez + 1.0f);
                s += th * vv[nt];
            }
            s += __shfl_xor(s, 1);
            s += __shfl_xor(s, 2);
            s += __shfl_xor(s, 4);
            s += __shfl_xor(s, 8);   // every lane in the lg-group has e[w]
            ev[mt * 4 + r] = s;
        }
    }

    // ---- softmax over 32 word slots, wave-local ----
    float mx = ev[0];
    #pragma unroll
    for (int j = 1; j < 8; ++j) mx = fmaxf(mx, ev[j]);
    mx = fmaxf(mx, __shfl_xor(mx, 16));
    mx = fmaxf(mx, __shfl_xor(mx, 32));
    float sc[8], sm = 0.0f;
    #pragma unroll
    for (int j = 0; j < 8; ++j) { sc[j] = __expf(ev[j] - mx); sm += sc[j]; }
    sm += __shfl_xor(sm, 16);
    sm += __shfl_xor(sm, 32);
    const float inv = 1.0f / sm;
    #pragma unroll
    for (int j = 0; j < 8; ++j) sc[j] *= inv;

    // ---- context: lane owns 8 consecutive d's; 6-deep pipelined gather ----
    float cx[8];
    #pragma unroll
    for (int j = 0; j < 8; ++j) cx[j] = 0.0f;

    #pragma unroll
    for (int w = 0; w < WW; ++w) {
        uint2 r = R[w % 6];                       // consume before slot reuse
        float s = __shfl(sc[(w >> 4) * 4 + (w & 3)], ((w >> 2) & 3) * 16);
        if (w + 6 < WW) cissue(w + 6, (w + 6) % 6);
        asm volatile("" ::: "memory");
        fp8x8_fma(cx, r, s);
    }

    const bool outmask = (n < node_sizes[b * CCC + c]) && (c < cross_lengths[b]);
    if (!outmask) {
        #pragma unroll
        for (int j = 0; j < 8; ++j) cx[j] = 0.0f;
    }
    float4* op = (float4*)(out + (size_t)t * DD + d0);
    op[0] = float4{cx[0], cx[1], cx[2], cx[3]};
    op[1] = float4{cx[4], cx[5], cx[6], cx[7]};
}

// ---------------- fp32/bf16 fallback (ws too small; not expected) ----------
__global__ __launch_bounds__(64) void prep_kernel(
    const float* __restrict__ con_hidden, const float* __restrict__ W_q,
    float* __restrict__ qout, float* __restrict__ hid_out)
{
    const int b = blockIdx.x;
    const int k = threadIdx.x;
    const float* h = con_hidden + b * DD;
    float acc = 0.0f;
    #pragma unroll 8
    for (int d = 0; d < DD; ++d) acc += h[d] * W_q[d * DKK + k];
    qout[b * DKK + k] = acc;
    const float4* src = (const float4*)h;
    float4* dst = (float4*)(hid_out + b * DD);
    for (int i = k; i < DD / 4; i += 64) dst[i] = src[i];
}

__global__ __launch_bounds__(64) void pack_wpre(
    const float* __restrict__ W_pre, bf16x8* __restrict__ wb)
{
    const int blk = blockIdx.x;
    const int ks = blk >> 2, nt = blk & 3;
    const int l  = threadIdx.x;
    const int lr = l & 15, lg = l >> 4;
    union { bf16x8 v; unsigned short s[8]; } u;
    #pragma unroll
    for (int j = 0; j < 8; ++j) {
        int k = ks * 32 + lg * 8 + j;
        u.s[j] = f2bf(W_pre[k * DKK + nt * 16 + lr]);
    }
    wb[blk * 64 + l] = u.v;
}

__global__ __launch_bounds__(256) void bag_kernel_f32(
    const int* __restrict__ token_ids, const int* __restrict__ node_lengths,
    const int* __restrict__ node_sizes, const int* __restrict__ cross_lengths,
    const float* __restrict__ embf, const float* __restrict__ b_pre,
    const float* __restrict__ v, const float* __restrict__ q,
    const bf16x8* __restrict__ wb, float* __restrict__ out)
{
    const int wid  = threadIdx.x >> 6;
    const int lane = threadIdx.x & 63;
    const int t = blockIdx.x * 4 + wid;
    const int b = t >> 7, cn = t & 127, c = cn >> 5, n = cn & 31;
    const int lr = lane & 15, lg = lane >> 4;

    const int L = node_lengths[t];
    const int* toks = token_ids + t * WW;
    int my_tok = 0;
    if (lane < 32 && lane < L) my_tok = toks[lane];
    const int tok0 = __shfl(my_tok, lr);
    const int tok1 = __shfl(my_tok, 16 + lr);
    const float* fp0 = embf + ((size_t)tok0 << 9) + lg * 8;
    const float* fp1 = embf + ((size_t)tok1 << 9) + lg * 8;

    f32x4 acc[2][4];
    #pragma unroll
    for (int mt = 0; mt < 2; ++mt)
        #pragma unroll
        for (int nt = 0; nt < 4; ++nt)
            acc[mt][nt] = (f32x4){0.f, 0.f, 0.f, 0.f};

    #pragma unroll 4
    for (int ks = 0; ks < 16; ++ks) {
        const float4* a0p = (const float4*)(fp0 + ks * 32);
        const float4* a1p = (const float4*)(fp1 + ks * 32);
        bf16x8 a0 = make_frag(a0p[0], a0p[1]);
        bf16x8 a1 = make_frag(a1p[0], a1p[1]);
        #pragma unroll
        for (int nt = 0; nt < 4; ++nt) {
            bf16x8 bb = wb[(ks * 4 + nt) * 64 + lane];
            acc[0][nt] = __builtin_amdgcn_mfma_f32_16x16x32_bf16(a0, bb, acc[0][nt], 0, 0, 0);
            acc[1][nt] = __builtin_amdgcn_mfma_f32_16x16x32_bf16(a1, bb, acc[1][nt], 0, 0, 0);
        }
    }

    float qb[4], vv[4];
    #pragma unroll
    for (int nt = 0; nt < 4; ++nt) {
        int cidx = nt * 16 + lr;
        qb[nt] = q[b * DKK + cidx] + b_pre[cidx];
        vv[nt] = v[cidx];
    }
    float ev[8];
    #pragma unroll
    for (int mt = 0; mt < 2; ++mt) {
        #pragma unroll
        for (int r = 0; r < 4; ++r) {
            float s = 0.0f;
            #pragma unroll
            for (int nt = 0; nt < 4; ++nt) {
                float pre = acc[mt][nt][r] + qb[nt];
                float ez = __expf(2.0f * pre);
                float th = 1.0f - 2.0f * __builtin_amdgcn_rcpf(ez + 1.0f);
                s += th * vv[nt];
            }
            s += __shfl_xor(s, 1); s += __shfl_xor(s, 2);
            s += __shfl_xor(s, 4); s += __shfl_xor(s, 8);
            ev[mt * 4 + r] = s;
        }
    }
    float mx = ev[0];
    #pragma unroll
    for (int j = 1; j < 8; ++j) mx = fmaxf(mx, ev[j]);
    mx = fmaxf(mx, __shfl_xor(mx, 16));
    mx = fmaxf(mx, __shfl_xor(mx, 32));
    float sc[8], sm = 0.0f;
    #pragma unroll
    for (int j = 0; j < 8; ++j) { sc[j] = __expf(ev[j] - mx); sm += sc[j]; }
    sm += __shfl_xor(sm, 16); sm += __shfl_xor(sm, 32);
    const float inv = 1.0f / sm;
    #pragma unroll
    for (int j = 0; j < 8; ++j) sc[j] *= inv;

    const int d0 = lane * 8;
    float cx[8];
    #pragma unroll
    for (int j = 0; j < 8; ++j) cx[j] = 0.0f;
    #pragma unroll
    for (int w = 0; w < WW; ++w) {
        int tk = __shfl(my_tok, w);
        float s = __shfl(sc[(w >> 4) * 4 + (w & 3)], ((w >> 2) & 3) * 16);
        const float4* pr = (const float4*)(embf + ((size_t)tk << 9) + d0);
        float4 x0 = pr[0], x1 = pr[1];
        cx[0] += s * x0.x; cx[1] += s * x0.y; cx[2] += s * x0.z; cx[3] += s * x0.w;
        cx[4] += s * x1.x; cx[5] += s * x1.y; cx[6] += s * x1.z; cx[7] += s * x1.w;
    }
    const bool outmask = (n < node_sizes[b * CCC + c]) && (c < cross_lengths[b]);
    if (!outmask) {
        #pragma unroll
        for (int j = 0; j < 8; ++j) cx[j] = 0.0f;
    }
    float4* op = (float4*)(out + (size_t)t * DD + d0);
    op[0] = float4{cx[0], cx[1], cx[2], cx[3]};
    op[1] = float4{cx[4], cx[5], cx[6], cx[7]};
}

extern "C" void kernel_launch(void* const* d_in, const int* in_sizes, int n_in,
                              void* d_out, int out_size, void* d_ws, size_t ws_size,
                              hipStream_t stream) {
    const int*   token_ids     = (const int*)d_in[0];
    const int*   node_lengths  = (const int*)d_in[1];
    const int*   node_sizes    = (const int*)d_in[2];
    const int*   cross_lengths = (const int*)d_in[3];
    const float* con_hidden    = (const float*)d_in[4];
    const float* emb           = (const float*)d_in[5];
    const float* W_pre         = (const float*)d_in[6];
    const float* b_pre         = (const float*)d_in[7];
    const float* W_q           = (const float*)d_in[8];
    const float* v             = (const float*)d_in[9];

    float*  out     = (float*)d_out;
    float*  hid_out = out + (size_t)TB * DD;                 // second output
    float*  q       = (float*)d_ws;                          // 16 KB
    // [16KB,80KB): wb region — fp8 path uses first 32 KB, fallback bf16 uses 64 KB
    uint2*  wb8     = (uint2*)((char*)d_ws + 16 * 1024);
    bf16x8* wb      = (bf16x8*)((char*)d_ws + 16 * 1024);
    unsigned char* emb8 = (unsigned char*)d_ws + 80 * 1024;  // 16 MB fp8 emb

    const size_t need = 80 * 1024 + (size_t)32000 * DD;

    if (ws_size >= need) {
        preproc_kernel<<<CONV_BLKS + 128, 256, 0, stream>>>(
            emb, emb8, con_hidden, W_q, q, hid_out, W_pre, wb8);
        bag_kernel<<<TB / 8, 512, 0, stream>>>(
            token_ids, node_lengths, node_sizes, cross_lengths,
            emb8, b_pre, v, q, wb8, out);
    } else {
        prep_kernel<<<64, 64, 0, stream>>>(con_hidden, W_q, q, hid_out);
        pack_wpre<<<64, 64, 0, stream>>>(W_pre, wb);
        bag_kernel_f32<<<TB / 4, 256, 0, stream>>>(
            token_ids, node_lengths, node_sizes, cross_lengths,
            emb, b_pre, v, q, wb, out);
    }
}

// Round 12
// 67.372 us; speedup vs baseline: 1.4176x; 1.1022x over previous
//
#include <hip/hip_runtime.h>
#include <hip/hip_bf16.h>

#define TB   8192   // B*C*N bags
#define WW   32     // words per bag
#define DD   512    // d_model
#define DKK  64     // attention dim
#define CCC  4      // max cross
#define VCB  32000  // vocab

using bf16x8 = __attribute__((ext_vector_type(8))) short;
using f32x4  = __attribute__((ext_vector_type(4))) float;
using f32x2  = __attribute__((ext_vector_type(2))) float;

__device__ __forceinline__ unsigned short f2bf(float x) {
    union { float f; unsigned u; } u;
    u.f = x;
    unsigned r = u.u + 0x7fffu + ((u.u >> 16) & 1u);
    return (unsigned short)(r >> 16);
}

__device__ __forceinline__ bf16x8 make_frag(float4 x, float4 y) {
    union { bf16x8 v; unsigned short s[8]; } u;
    u.s[0] = f2bf(x.x); u.s[1] = f2bf(x.y); u.s[2] = f2bf(x.z); u.s[3] = f2bf(x.w);
    u.s[4] = f2bf(y.x); u.s[5] = f2bf(y.y); u.s[6] = f2bf(y.z); u.s[7] = f2bf(y.w);
    return u.v;
}

// pack 8 fp32 -> 8 fp8 e4m3 (HW cvt, RNE) as uint2; byte j == element j
__device__ __forceinline__ uint2 pack_fp8x8(float4 a, float4 b) {
    int lo = 0, hi = 0;
    lo = __builtin_amdgcn_cvt_pk_fp8_f32(a.x, a.y, lo, false);
    lo = __builtin_amdgcn_cvt_pk_fp8_f32(a.z, a.w, lo, true);
    hi = __builtin_amdgcn_cvt_pk_fp8_f32(b.x, b.y, hi, false);
    hi = __builtin_amdgcn_cvt_pk_fp8_f32(b.z, b.w, hi, true);
    uint2 r; r.x = (unsigned)lo; r.y = (unsigned)hi;
    return r;
}

__device__ __forceinline__ long long u2l(uint2 u) {
    union { uint2 v; long long l; } c; c.v = u; return c.l;
}

// fma 8 fp8 elems into fp32 accumulators: cx[j] += s * elem[j]
__device__ __forceinline__ void fp8x8_fma(float* cx, uint2 r, float s) {
    f32x2 f01 = __builtin_amdgcn_cvt_pk_f32_fp8((int)r.x, false);
    f32x2 f23 = __builtin_amdgcn_cvt_pk_f32_fp8((int)r.x, true);
    f32x2 f45 = __builtin_amdgcn_cvt_pk_f32_fp8((int)r.y, false);
    f32x2 f67 = __builtin_amdgcn_cvt_pk_f32_fp8((int)r.y, true);
    cx[0] += s * f01[0]; cx[1] += s * f01[1];
    cx[2] += s * f23[0]; cx[3] += s * f23[1];
    cx[4] += s * f45[0]; cx[5] += s * f45[1];
    cx[6] += s * f67[0]; cx[7] += s * f67[1];
}

// ---------------- k1: prep (q GEMV, parallel) + pack W_pre fp8 frags ----------
// blocks 0-63  : b = blk; q[b,k] = con_hidden[b,:]·W_q[:,k]; copy hidden row
// blocks 64-127: pack W_pre fragment fb = blk-64
__global__ __launch_bounds__(256) void prep_pack(
    const float* __restrict__ con_hidden,  // [64][512]
    const float* __restrict__ W_q,         // [512][64]
    const float* __restrict__ W_pre,       // [512][64]
    float* __restrict__ qout,              // [64][64]
    float* __restrict__ hid_out,           // [64][512]
    uint2* __restrict__ wb8)               // 64 frags * 64 lanes * 8B
{
    const int blk = blockIdx.x;
    const int tid = threadIdx.x;
    if (blk < 64) {
        __shared__ float red[256];
        const int b = blk;
        const int k = tid & 63, qtr = tid >> 6;
        const float* h = con_hidden + b * DD;
        float acc = 0.0f;
        const int d0 = qtr * 128;
        #pragma unroll 8
        for (int d = 0; d < 128; ++d) acc += h[d0 + d] * W_q[(d0 + d) * DKK + k];
        red[tid] = acc;
        __syncthreads();
        if (tid < 64)
            qout[b * DKK + tid] = red[tid] + red[64 + tid] + red[128 + tid] + red[192 + tid];
        // hidden copy (128 float4s, 256 threads -> each first 128 do one)
        if (tid < 128) {
            const float4* src = (const float4*)h;
            ((float4*)(hid_out + b * DD))[tid] = src[tid];
        }
    } else {
        if (tid >= 64) return;
        const int fb = blk - 64;               // ks*4 + nt
        const int ks = fb >> 2, nt = fb & 3;
        const int lr = tid & 15, lg = tid >> 4;
        float w[8];
        #pragma unroll
        for (int j = 0; j < 8; ++j)
            w[j] = W_pre[(ks * 32 + lg * 8 + j) * DKK + nt * 16 + lr];
        wb8[fb * 64 + tid] = pack_fp8x8(float4{w[0], w[1], w[2], w[3]},
                                        float4{w[4], w[5], w[6], w[7]});
    }
}

// ---------------- k2: fused emb fp32->fp8 conversion + P = emb @ W_pre -------
// 500 blocks x 256 thr (4 waves). Block handles 64 vocab rows (wave: 16 rows).
// Reads each emb row ONCE: converts+stores fp8, and MFMAs into P.
__global__ __launch_bounds__(256) void conv_gemm(
    const float* __restrict__ emb,         // [32000][512] fp32
    unsigned char* __restrict__ emb8,      // [32000*512] fp8 out
    float* __restrict__ P,                 // [32000][64] out
    const uint2* __restrict__ wb8)         // packed W_pre fp8 fragments
{
    const int tid  = threadIdx.x;
    const int wid  = tid >> 6;
    const int lane = tid & 63;
    const int lr = lane & 15, lg = lane >> 4;
    const int base = blockIdx.x * 64 + wid * 16;   // this wave's 16 rows

    __shared__ uint2 swb[4096];   // 32 KB W_pre fp8 fragments
    #pragma unroll
    for (int i = tid; i < 4096; i += 256) swb[i] = wb8[i];
    __syncthreads();

    const float* arow = emb + (size_t)(base + lr) * DD + lg * 8;
    unsigned char* erow = emb8 + (size_t)(base + lr) * DD + lg * 8;

    f32x4 accP[4];
    #pragma unroll
    for (int nt = 0; nt < 4; ++nt) accP[nt] = (f32x4){0.f, 0.f, 0.f, 0.f};

    #pragma unroll 4
    for (int ks = 0; ks < 16; ++ks) {
        const float4* p = (const float4*)(arow + ks * 32);
        float4 x = p[0], y = p[1];
        uint2 a8 = pack_fp8x8(x, y);
        *(uint2*)(erow + ks * 32) = a8;
        long long a = u2l(a8);
        #pragma unroll
        for (int nt = 0; nt < 4; ++nt) {
            long long bfr = u2l(swb[(ks * 4 + nt) * 64 + lane]);
            accP[nt] = __builtin_amdgcn_mfma_f32_16x16x32_fp8_fp8(a, bfr, accP[nt], 0, 0, 0);
        }
    }

    // C layout: col = nt*16 + lr, row = lg*4 + r  (verified mapping, r1-r11)
    #pragma unroll
    for (int nt = 0; nt < 4; ++nt)
        #pragma unroll
        for (int r = 0; r < 4; ++r)
            P[(size_t)(base + lg * 4 + r) * DKK + nt * 16 + lr] = accP[nt][r];
}

// ---------------- k3: bag kernel — P gather + lane-local softmax + fp8 context
// 1024 blocks x 512 thr, one bag per wave, NO LDS, no barriers.
__global__ __launch_bounds__(512) void bag_kernel(
    const int* __restrict__ token_ids,     // [8192][32]
    const int* __restrict__ node_lengths,  // [8192]
    const int* __restrict__ node_sizes,    // [256]
    const int* __restrict__ cross_lengths, // [64]
    const unsigned char* __restrict__ emb8, // [32000*512] fp8, row 0 zeros
    const float* __restrict__ P,           // [32000][64] pre-projections
    const float* __restrict__ b_pre,       // [64]
    const float* __restrict__ v,           // [64]
    const float* __restrict__ q,           // [64][64]
    float* __restrict__ out)               // [8192][512]
{
    const int tid  = threadIdx.x;
    const int wid  = tid >> 6;
    const int lane = tid & 63;             // lane == k index
    const int t = blockIdx.x * 8 + wid;
    const int b = t >> 7, cn = t & 127, c = cn >> 5, n = cn & 31;

    const int L = node_lengths[t];
    const int* toks = token_ids + t * WW;

    int my_tok = 0;
    if (lane < 32 && lane < L) my_tok = toks[lane];   // emb/P row 0 is zero

    const float qb = q[b * DKK + lane] + b_pre[lane];
    const float vv = v[lane];

    // ---- P-row gather, 8-deep pipeline ----
    float Pv[8];
    auto pissue = [&](int w, int sl) {
        int tk = __shfl(my_tok, w);
        Pv[sl] = P[(size_t)tk * DKK + lane];
    };
    pissue(0, 0); pissue(1, 1); pissue(2, 2); pissue(3, 3);
    pissue(4, 4); pissue(5, 5); pissue(6, 6); pissue(7, 7);
    asm volatile("" ::: "memory");

    // ---- context-row prefetch starts now (addresses need only my_tok) ----
    const int d0 = lane * 8;
    uint2 R[6];
    auto cissue = [&](int w, int sl) {
        int tk = __shfl(my_tok, w);
        R[sl] = *(const uint2*)(emb8 + ((size_t)tk << 9) + d0);
    };
    cissue(0, 0); cissue(1, 1); cissue(2, 2);
    cissue(3, 3); cissue(4, 4); cissue(5, 5);
    asm volatile("" ::: "memory");

    // ---- energy: e[w] = sum_k tanh(P[tok_w][k] + qb) * v[k]; butterfly
    //      reduce replicates e[w] to all lanes -> softmax is lane-local.
    float sc[32];
    #pragma unroll
    for (int w = 0; w < WW; ++w) {
        float pv = Pv[w & 7];
        if (w + 8 < WW) pissue(w + 8, w & 7);
        asm volatile("" ::: "memory");
        float ez = __expf(2.0f * (pv + qb));             // tanh via exp
        float th = 1.0f - 2.0f * __builtin_amdgcn_rcpf(ez + 1.0f);
        float e = th * vv;
        e += __shfl_xor(e, 1);  e += __shfl_xor(e, 2);
        e += __shfl_xor(e, 4);  e += __shfl_xor(e, 8);
        e += __shfl_xor(e, 16); e += __shfl_xor(e, 32);
        sc[w] = e;
    }

    // ---- softmax over the 32 energies (replicated in-lane, no shuffles) ----
    float mx = sc[0];
    #pragma unroll
    for (int j = 1; j < 32; ++j) mx = fmaxf(mx, sc[j]);
    float sm = 0.0f;
    #pragma unroll
    for (int j = 0; j < 32; ++j) { sc[j] = __expf(sc[j] - mx); sm += sc[j]; }
    const float inv = 1.0f / sm;
    #pragma unroll
    for (int j = 0; j < 32; ++j) sc[j] *= inv;

    // ---- context: lane owns 8 consecutive d's; 6-deep fp8 gather ----
    float cx[8];
    #pragma unroll
    for (int j = 0; j < 8; ++j) cx[j] = 0.0f;

    #pragma unroll
    for (int w = 0; w < WW; ++w) {
        uint2 r = R[w % 6];
        float s = sc[w];                      // direct register, no shfl
        if (w + 6 < WW) cissue(w + 6, (w + 6) % 6);
        asm volatile("" ::: "memory");
        fp8x8_fma(cx, r, s);
    }

    const bool outmask = (n < node_sizes[b * CCC + c]) && (c < cross_lengths[b]);
    if (!outmask) {
        #pragma unroll
        for (int j = 0; j < 8; ++j) cx[j] = 0.0f;
    }
    float4* op = (float4*)(out + (size_t)t * DD + d0);
    op[0] = float4{cx[0], cx[1], cx[2], cx[3]};
    op[1] = float4{cx[4], cx[5], cx[6], cx[7]};
}

// ---------------- fp32/bf16 fallback (ws too small; not expected) ----------
__global__ __launch_bounds__(64) void prep_kernel(
    const float* __restrict__ con_hidden, const float* __restrict__ W_q,
    float* __restrict__ qout, float* __restrict__ hid_out)
{
    const int b = blockIdx.x;
    const int k = threadIdx.x;
    const float* h = con_hidden + b * DD;
    float acc = 0.0f;
    #pragma unroll 8
    for (int d = 0; d < DD; ++d) acc += h[d] * W_q[d * DKK + k];
    qout[b * DKK + k] = acc;
    const float4* src = (const float4*)h;
    float4* dst = (float4*)(hid_out + b * DD);
    for (int i = k; i < DD / 4; i += 64) dst[i] = src[i];
}

__global__ __launch_bounds__(64) void pack_wpre(
    const float* __restrict__ W_pre, bf16x8* __restrict__ wb)
{
    const int blk = blockIdx.x;
    const int ks = blk >> 2, nt = blk & 3;
    const int l  = threadIdx.x;
    const int lr = l & 15, lg = l >> 4;
    union { bf16x8 v; unsigned short s[8]; } u;
    #pragma unroll
    for (int j = 0; j < 8; ++j) {
        int k = ks * 32 + lg * 8 + j;
        u.s[j] = f2bf(W_pre[k * DKK + nt * 16 + lr]);
    }
    wb[blk * 64 + l] = u.v;
}

__global__ __launch_bounds__(256) void bag_kernel_f32(
    const int* __restrict__ token_ids, const int* __restrict__ node_lengths,
    const int* __restrict__ node_sizes, const int* __restrict__ cross_lengths,
    const float* __restrict__ embf, const float* __restrict__ b_pre,
    const float* __restrict__ v, const float* __restrict__ q,
    const bf16x8* __restrict__ wb, float* __restrict__ out)
{
    const int wid  = threadIdx.x >> 6;
    const int lane = threadIdx.x & 63;
    const int t = blockIdx.x * 4 + wid;
    const int b = t >> 7, cn = t & 127, c = cn >> 5, n = cn & 31;
    const int lr = lane & 15, lg = lane >> 4;

    const int L = node_lengths[t];
    const int* toks = token_ids + t * WW;
    int my_tok = 0;
    if (lane < 32 && lane < L) my_tok = toks[lane];
    const int tok0 = __shfl(my_tok, lr);
    const int tok1 = __shfl(my_tok, 16 + lr);
    const float* fp0 = embf + ((size_t)tok0 << 9) + lg * 8;
    const float* fp1 = embf + ((size_t)tok1 << 9) + lg * 8;

    f32x4 acc[2][4];
    #pragma unroll
    for (int mt = 0; mt < 2; ++mt)
        #pragma unroll
        for (int nt = 0; nt < 4; ++nt)
            acc[mt][nt] = (f32x4){0.f, 0.f, 0.f, 0.f};

    #pragma unroll 4
    for (int ks = 0; ks < 16; ++ks) {
        const float4* a0p = (const float4*)(fp0 + ks * 32);
        const float4* a1p = (const float4*)(fp1 + ks * 32);
        bf16x8 a0 = make_frag(a0p[0], a0p[1]);
        bf16x8 a1 = make_frag(a1p[0], a1p[1]);
        #pragma unroll
        for (int nt = 0; nt < 4; ++nt) {
            bf16x8 bb = wb[(ks * 4 + nt) * 64 + lane];
            acc[0][nt] = __builtin_amdgcn_mfma_f32_16x16x32_bf16(a0, bb, acc[0][nt], 0, 0, 0);
            acc[1][nt] = __builtin_amdgcn_mfma_f32_16x16x32_bf16(a1, bb, acc[1][nt], 0, 0, 0);
        }
    }

    float qb[4], vv[4];
    #pragma unroll
    for (int nt = 0; nt < 4; ++nt) {
        int cidx = nt * 16 + lr;
        qb[nt] = q[b * DKK + cidx] + b_pre[cidx];
        vv[nt] = v[cidx];
    }
    float ev[8];
    #pragma unroll
    for (int mt = 0; mt < 2; ++mt) {
        #pragma unroll
        for (int r = 0; r < 4; ++r) {
            float s = 0.0f;
            #pragma unroll
            for (int nt = 0; nt < 4; ++nt) {
                float pre = acc[mt][nt][r] + qb[nt];
                float ez = __expf(2.0f * pre);
                float th = 1.0f - 2.0f * __builtin_amdgcn_rcpf(ez + 1.0f);
                s += th * vv[nt];
            }
            s += __shfl_xor(s, 1); s += __shfl_xor(s, 2);
            s += __shfl_xor(s, 4); s += __shfl_xor(s, 8);
            ev[mt * 4 + r] = s;
        }
    }
    float mx = ev[0];
    #pragma unroll
    for (int j = 1; j < 8; ++j) mx = fmaxf(mx, ev[j]);
    mx = fmaxf(mx, __shfl_xor(mx, 16));
    mx = fmaxf(mx, __shfl_xor(mx, 32));
    float sc[8], sm = 0.0f;
    #pragma unroll
    for (int j = 0; j < 8; ++j) { sc[j] = __expf(ev[j] - mx); sm += sc[j]; }
    sm += __shfl_xor(sm, 16); sm += __shfl_xor(sm, 32);
    const float inv = 1.0f / sm;
    #pragma unroll
    for (int j = 0; j < 8; ++j) sc[j] *= inv;

    const int d0 = lane * 8;
    float cx[8];
    #pragma unroll
    for (int j = 0; j < 8; ++j) cx[j] = 0.0f;
    #pragma unroll
    for (int w = 0; w < WW; ++w) {
        int tk = __shfl(my_tok, w);
        float s = __shfl(sc[(w >> 4) * 4 + (w & 3)], ((w >> 2) & 3) * 16);
        const float4* pr = (const float4*)(embf + ((size_t)tk << 9) + d0);
        float4 x0 = pr[0], x1 = pr[1];
        cx[0] += s * x0.x; cx[1] += s * x0.y; cx[2] += s * x0.z; cx[3] += s * x0.w;
        cx[4] += s * x1.x; cx[5] += s * x1.y; cx[6] += s * x1.z; cx[7] += s * x1.w;
    }
    const bool outmask = (n < node_sizes[b * CCC + c]) && (c < cross_lengths[b]);
    if (!outmask) {
        #pragma unroll
        for (int j = 0; j < 8; ++j) cx[j] = 0.0f;
    }
    float4* op = (float4*)(out + (size_t)t * DD + d0);
    op[0] = float4{cx[0], cx[1], cx[2], cx[3]};
    op[1] = float4{cx[4], cx[5], cx[6], cx[7]};
}

extern "C" void kernel_launch(void* const* d_in, const int* in_sizes, int n_in,
                              void* d_out, int out_size, void* d_ws, size_t ws_size,
                              hipStream_t stream) {
    const int*   token_ids     = (const int*)d_in[0];
    const int*   node_lengths  = (const int*)d_in[1];
    const int*   node_sizes    = (const int*)d_in[2];
    const int*   cross_lengths = (const int*)d_in[3];
    const float* con_hidden    = (const float*)d_in[4];
    const float* emb           = (const float*)d_in[5];
    const float* W_pre         = (const float*)d_in[6];
    const float* b_pre         = (const float*)d_in[7];
    const float* W_q           = (const float*)d_in[8];
    const float* v             = (const float*)d_in[9];

    float*  out     = (float*)d_out;
    float*  hid_out = out + (size_t)TB * DD;                  // second output
    float*  q       = (float*)d_ws;                           // 16 KB
    uint2*  wb8     = (uint2*)((char*)d_ws + 16 * 1024);      // 32 KB fp8 frags
    bf16x8* wb      = (bf16x8*)((char*)d_ws + 16 * 1024);     // fallback bf16 frags
    float*  P       = (float*)((char*)d_ws + 80 * 1024);      // 8 MB pre-proj
    unsigned char* emb8 = (unsigned char*)d_ws + 80 * 1024 + (size_t)VCB * DKK * 4;

    const size_t need = 80 * 1024 + (size_t)VCB * DKK * 4 + (size_t)VCB * DD;

    if (ws_size >= need) {
        prep_pack<<<128, 256, 0, stream>>>(con_hidden, W_q, W_pre, q, hid_out, wb8);
        conv_gemm<<<VCB / 64, 256, 0, stream>>>(emb, emb8, P, wb8);
        bag_kernel<<<TB / 8, 512, 0, stream>>>(
            token_ids, node_lengths, node_sizes, cross_lengths,
            emb8, P, b_pre, v, q, out);
    } else {
        prep_kernel<<<64, 64, 0, stream>>>(con_hidden, W_q, q, hid_out);
        pack_wpre<<<64, 64, 0, stream>>>(W_pre, wb);
        bag_kernel_f32<<<TB / 4, 256, 0, stream>>>(
            token_ids, node_lengths, node_sizes, cross_lengths,
            emb, b_pre, v, q, wb, out);
    }
}

// Round 13
// 67.051 us; speedup vs baseline: 1.4244x; 1.0048x over previous
//
#include <hip/hip_runtime.h>
#include <hip/hip_bf16.h>

#define TB   8192   // B*C*N bags
#define WW   32     // words per bag
#define DD   512    // d_model
#define DKK  64     // attention dim
#define CCC  4      // max cross
#define VCB  32000  // vocab

using bf16x8 = __attribute__((ext_vector_type(8))) short;
using f32x4  = __attribute__((ext_vector_type(4))) float;
using f32x2  = __attribute__((ext_vector_type(2))) float;

__device__ __forceinline__ unsigned short f2bf(float x) {
    union { float f; unsigned u; } u;
    u.f = x;
    unsigned r = u.u + 0x7fffu + ((u.u >> 16) & 1u);
    return (unsigned short)(r >> 16);
}

__device__ __forceinline__ bf16x8 make_frag(float4 x, float4 y) {
    union { bf16x8 v; unsigned short s[8]; } u;
    u.s[0] = f2bf(x.x); u.s[1] = f2bf(x.y); u.s[2] = f2bf(x.z); u.s[3] = f2bf(x.w);
    u.s[4] = f2bf(y.x); u.s[5] = f2bf(y.y); u.s[6] = f2bf(y.z); u.s[7] = f2bf(y.w);
    return u.v;
}

// pack 8 fp32 -> 8 fp8 e4m3 (HW cvt, RNE) as uint2; byte j == element j
__device__ __forceinline__ uint2 pack_fp8x8(float4 a, float4 b) {
    int lo = 0, hi = 0;
    lo = __builtin_amdgcn_cvt_pk_fp8_f32(a.x, a.y, lo, false);
    lo = __builtin_amdgcn_cvt_pk_fp8_f32(a.z, a.w, lo, true);
    hi = __builtin_amdgcn_cvt_pk_fp8_f32(b.x, b.y, hi, false);
    hi = __builtin_amdgcn_cvt_pk_fp8_f32(b.z, b.w, hi, true);
    uint2 r; r.x = (unsigned)lo; r.y = (unsigned)hi;
    return r;
}

__device__ __forceinline__ long long u2l(uint2 u) {
    union { uint2 v; long long l; } c; c.v = u; return c.l;
}

// fma 8 fp8 elems into fp32 accumulators: cx[j] += s * elem[j]
__device__ __forceinline__ void fp8x8_fma(float* cx, uint2 r, float s) {
    f32x2 f01 = __builtin_amdgcn_cvt_pk_f32_fp8((int)r.x, false);
    f32x2 f23 = __builtin_amdgcn_cvt_pk_f32_fp8((int)r.x, true);
    f32x2 f45 = __builtin_amdgcn_cvt_pk_f32_fp8((int)r.y, false);
    f32x2 f67 = __builtin_amdgcn_cvt_pk_f32_fp8((int)r.y, true);
    cx[0] += s * f01[0]; cx[1] += s * f01[1];
    cx[2] += s * f23[0]; cx[3] += s * f23[1];
    cx[4] += s * f45[0]; cx[5] += s * f45[1];
    cx[6] += s * f67[0]; cx[7] += s * f67[1];
}

// ---------------- k1: prep (q GEMV, parallel) + pack W_pre fp8 frags ----------
__global__ __launch_bounds__(256) void prep_pack(
    const float* __restrict__ con_hidden,  // [64][512]
    const float* __restrict__ W_q,         // [512][64]
    const float* __restrict__ W_pre,       // [512][64]
    float* __restrict__ qout,              // [64][64]
    float* __restrict__ hid_out,           // [64][512]
    uint2* __restrict__ wb8)               // 64 frags * 64 lanes * 8B
{
    const int blk = blockIdx.x;
    const int tid = threadIdx.x;
    if (blk < 64) {
        __shared__ float red[256];
        const int b = blk;
        const int k = tid & 63, qtr = tid >> 6;
        const float* h = con_hidden + b * DD;
        float acc = 0.0f;
        const int d0 = qtr * 128;
        #pragma unroll 8
        for (int d = 0; d < 128; ++d) acc += h[d0 + d] * W_q[(d0 + d) * DKK + k];
        red[tid] = acc;
        __syncthreads();
        if (tid < 64)
            qout[b * DKK + tid] = red[tid] + red[64 + tid] + red[128 + tid] + red[192 + tid];
        if (tid < 128) {
            const float4* src = (const float4*)h;
            ((float4*)(hid_out + b * DD))[tid] = src[tid];
        }
    } else {
        if (tid >= 64) return;
        const int fb = blk - 64;               // ks*4 + nt
        const int ks = fb >> 2, nt = fb & 3;
        const int lr = tid & 15, lg = tid >> 4;
        float w[8];
        #pragma unroll
        for (int j = 0; j < 8; ++j)
            w[j] = W_pre[(ks * 32 + lg * 8 + j) * DKK + nt * 16 + lr];
        wb8[fb * 64 + tid] = pack_fp8x8(float4{w[0], w[1], w[2], w[3]},
                                        float4{w[4], w[5], w[6], w[7]});
    }
}

// ---------------- k2: fused emb fp32->fp8 conversion + P = emb @ W_pre (bf16)
__global__ __launch_bounds__(256) void conv_gemm(
    const float* __restrict__ emb,         // [32000][512] fp32
    unsigned char* __restrict__ emb8,      // [32000*512] fp8 out
    unsigned short* __restrict__ P,        // [32000][64] bf16 out
    const uint2* __restrict__ wb8)         // packed W_pre fp8 fragments
{
    const int tid  = threadIdx.x;
    const int wid  = tid >> 6;
    const int lane = tid & 63;
    const int lr = lane & 15, lg = lane >> 4;
    const int base = blockIdx.x * 64 + wid * 16;   // this wave's 16 rows

    __shared__ uint2 swb[4096];   // 32 KB W_pre fp8 fragments
    #pragma unroll
    for (int i = tid; i < 4096; i += 256) swb[i] = wb8[i];
    __syncthreads();

    const float* arow = emb + (size_t)(base + lr) * DD + lg * 8;
    unsigned char* erow = emb8 + (size_t)(base + lr) * DD + lg * 8;

    f32x4 accP[4];
    #pragma unroll
    for (int nt = 0; nt < 4; ++nt) accP[nt] = (f32x4){0.f, 0.f, 0.f, 0.f};

    #pragma unroll 4
    for (int ks = 0; ks < 16; ++ks) {
        const float4* p = (const float4*)(arow + ks * 32);
        float4 x = p[0], y = p[1];
        uint2 a8 = pack_fp8x8(x, y);
        *(uint2*)(erow + ks * 32) = a8;
        long long a = u2l(a8);
        #pragma unroll
        for (int nt = 0; nt < 4; ++nt) {
            long long bfr = u2l(swb[(ks * 4 + nt) * 64 + lane]);
            accP[nt] = __builtin_amdgcn_mfma_f32_16x16x32_fp8_fp8(a, bfr, accP[nt], 0, 0, 0);
        }
    }

    // C layout: col = nt*16 + lr, row = lg*4 + r
    #pragma unroll
    for (int nt = 0; nt < 4; ++nt)
        #pragma unroll
        for (int r = 0; r < 4; ++r)
            P[(size_t)(base + lg * 4 + r) * DKK + nt * 16 + lr] = f2bf(accP[nt][r]);
}

// ---------------- k3: bag kernel — bf16 P gather + lane-local softmax + fp8 ctx
__global__ __launch_bounds__(512) void bag_kernel(
    const int* __restrict__ token_ids,     // [8192][32]
    const int* __restrict__ node_lengths,  // [8192]
    const int* __restrict__ node_sizes,    // [256]
    const int* __restrict__ cross_lengths, // [64]
    const unsigned char* __restrict__ emb8, // [32000*512] fp8, row 0 zeros
    const unsigned short* __restrict__ P,  // [32000][64] bf16 pre-projections
    const float* __restrict__ b_pre,       // [64]
    const float* __restrict__ v,           // [64]
    const float* __restrict__ q,           // [64][64]
    float* __restrict__ out)               // [8192][512]
{
    const int tid  = threadIdx.x;
    const int wid  = tid >> 6;
    const int lane = tid & 63;             // lane == k index
    const int t = blockIdx.x * 8 + wid;
    const int b = t >> 7, cn = t & 127, c = cn >> 5, n = cn & 31;

    const int L = node_lengths[t];
    const int* toks = token_ids + t * WW;

    int my_tok = 0;
    if (lane < 32 && lane < L) my_tok = toks[lane];   // emb/P row 0 is zero

    const float qb = q[b * DKK + lane] + b_pre[lane];
    const float vv = v[lane];

    // ---- P-row gather (bf16), 8-deep pipeline ----
    unsigned short Pu[8];
    auto pissue = [&](int w, int sl) {
        int tk = __shfl(my_tok, w);
        Pu[sl] = P[(size_t)tk * DKK + lane];
    };
    pissue(0, 0); pissue(1, 1); pissue(2, 2); pissue(3, 3);
    pissue(4, 4); pissue(5, 5); pissue(6, 6); pissue(7, 7);
    asm volatile("" ::: "memory");

    // ---- context-row prefetch starts now (addresses need only my_tok) ----
    const int d0 = lane * 8;
    uint2 R[6];
    auto cissue = [&](int w, int sl) {
        int tk = __shfl(my_tok, w);
        R[sl] = *(const uint2*)(emb8 + ((size_t)tk << 9) + d0);
    };
    cissue(0, 0); cissue(1, 1); cissue(2, 2);
    cissue(3, 3); cissue(4, 4); cissue(5, 5);
    asm volatile("" ::: "memory");

    // ---- energy: e[w] = sum_k tanh(P[tok_w][k] + qb) * v[k]; butterfly
    float sc[32];
    #pragma unroll
    for (int w = 0; w < WW; ++w) {
        float pv = __uint_as_float((unsigned)Pu[w & 7] << 16);
        if (w + 8 < WW) pissue(w + 8, w & 7);
        asm volatile("" ::: "memory");
        float ez = __expf(2.0f * (pv + qb));             // tanh via exp
        float th = 1.0f - 2.0f * __builtin_amdgcn_rcpf(ez + 1.0f);
        float e = th * vv;
        e += __shfl_xor(e, 1);  e += __shfl_xor(e, 2);
        e += __shfl_xor(e, 4);  e += __shfl_xor(e, 8);
        e += __shfl_xor(e, 16); e += __shfl_xor(e, 32);
        sc[w] = e;
    }

    // ---- softmax over the 32 energies (replicated in-lane) ----
    float mx = sc[0];
    #pragma unroll
    for (int j = 1; j < 32; ++j) mx = fmaxf(mx, sc[j]);
    float sm = 0.0f;
    #pragma unroll
    for (int j = 0; j < 32; ++j) { sc[j] = __expf(sc[j] - mx); sm += sc[j]; }
    const float inv = 1.0f / sm;
    #pragma unroll
    for (int j = 0; j < 32; ++j) sc[j] *= inv;

    // ---- context: lane owns 8 consecutive d's; 6-deep fp8 gather ----
    float cx[8];
    #pragma unroll
    for (int j = 0; j < 8; ++j) cx[j] = 0.0f;

    #pragma unroll
    for (int w = 0; w < WW; ++w) {
        uint2 r = R[w % 6];
        float s = sc[w];
        if (w + 6 < WW) cissue(w + 6, (w + 6) % 6);
        asm volatile("" ::: "memory");
        fp8x8_fma(cx, r, s);
    }

    const bool outmask = (n < node_sizes[b * CCC + c]) && (c < cross_lengths[b]);
    if (!outmask) {
        #pragma unroll
        for (int j = 0; j < 8; ++j) cx[j] = 0.0f;
    }
    float4* op = (float4*)(out + (size_t)t * DD + d0);
    op[0] = float4{cx[0], cx[1], cx[2], cx[3]};
    op[1] = float4{cx[4], cx[5], cx[6], cx[7]};
}

// ---------------- fp32/bf16 fallback (ws too small; not expected) ----------
__global__ __launch_bounds__(64) void prep_kernel(
    const float* __restrict__ con_hidden, const float* __restrict__ W_q,
    float* __restrict__ qout, float* __restrict__ hid_out)
{
    const int b = blockIdx.x;
    const int k = threadIdx.x;
    const float* h = con_hidden + b * DD;
    float acc = 0.0f;
    #pragma unroll 8
    for (int d = 0; d < DD; ++d) acc += h[d] * W_q[d * DKK + k];
    qout[b * DKK + k] = acc;
    const float4* src = (const float4*)h;
    float4* dst = (float4*)(hid_out + b * DD);
    for (int i = k; i < DD / 4; i += 64) dst[i] = src[i];
}

__global__ __launch_bounds__(64) void pack_wpre(
    const float* __restrict__ W_pre, bf16x8* __restrict__ wb)
{
    const int blk = blockIdx.x;
    const int ks = blk >> 2, nt = blk & 3;
    const int l  = threadIdx.x;
    const int lr = l & 15, lg = l >> 4;
    union { bf16x8 v; unsigned short s[8]; } u;
    #pragma unroll
    for (int j = 0; j < 8; ++j) {
        int k = ks * 32 + lg * 8 + j;
        u.s[j] = f2bf(W_pre[k * DKK + nt * 16 + lr]);
    }
    wb[blk * 64 + l] = u.v;
}

__global__ __launch_bounds__(256) void bag_kernel_f32(
    const int* __restrict__ token_ids, const int* __restrict__ node_lengths,
    const int* __restrict__ node_sizes, const int* __restrict__ cross_lengths,
    const float* __restrict__ embf, const float* __restrict__ b_pre,
    const float* __restrict__ v, const float* __restrict__ q,
    const bf16x8* __restrict__ wb, float* __restrict__ out)
{
    const int wid  = threadIdx.x >> 6;
    const int lane = threadIdx.x & 63;
    const int t = blockIdx.x * 4 + wid;
    const int b = t >> 7, cn = t & 127, c = cn >> 5, n = cn & 31;
    const int lr = lane & 15, lg = lane >> 4;

    const int L = node_lengths[t];
    const int* toks = token_ids + t * WW;
    int my_tok = 0;
    if (lane < 32 && lane < L) my_tok = toks[lane];
    const int tok0 = __shfl(my_tok, lr);
    const int tok1 = __shfl(my_tok, 16 + lr);
    const float* fp0 = embf + ((size_t)tok0 << 9) + lg * 8;
    const float* fp1 = embf + ((size_t)tok1 << 9) + lg * 8;

    f32x4 acc[2][4];
    #pragma unroll
    for (int mt = 0; mt < 2; ++mt)
        #pragma unroll
        for (int nt = 0; nt < 4; ++nt)
            acc[mt][nt] = (f32x4){0.f, 0.f, 0.f, 0.f};

    #pragma unroll 4
    for (int ks = 0; ks < 16; ++ks) {
        const float4* a0p = (const float4*)(fp0 + ks * 32);
        const float4* a1p = (const float4*)(fp1 + ks * 32);
        bf16x8 a0 = make_frag(a0p[0], a0p[1]);
        bf16x8 a1 = make_frag(a1p[0], a1p[1]);
        #pragma unroll
        for (int nt = 0; nt < 4; ++nt) {
            bf16x8 bb = wb[(ks * 4 + nt) * 64 + lane];
            acc[0][nt] = __builtin_amdgcn_mfma_f32_16x16x32_bf16(a0, bb, acc[0][nt], 0, 0, 0);
            acc[1][nt] = __builtin_amdgcn_mfma_f32_16x16x32_bf16(a1, bb, acc[1][nt], 0, 0, 0);
        }
    }

    float qb[4], vv[4];
    #pragma unroll
    for (int nt = 0; nt < 4; ++nt) {
        int cidx = nt * 16 + lr;
        qb[nt] = q[b * DKK + cidx] + b_pre[cidx];
        vv[nt] = v[cidx];
    }
    float ev[8];
    #pragma unroll
    for (int mt = 0; mt < 2; ++mt) {
        #pragma unroll
        for (int r = 0; r < 4; ++r) {
            float s = 0.0f;
            #pragma unroll
            for (int nt = 0; nt < 4; ++nt) {
                float pre = acc[mt][nt][r] + qb[nt];
                float ez = __expf(2.0f * pre);
                float th = 1.0f - 2.0f * __builtin_amdgcn_rcpf(ez + 1.0f);
                s += th * vv[nt];
            }
            s += __shfl_xor(s, 1); s += __shfl_xor(s, 2);
            s += __shfl_xor(s, 4); s += __shfl_xor(s, 8);
            ev[mt * 4 + r] = s;
        }
    }
    float mx = ev[0];
    #pragma unroll
    for (int j = 1; j < 8; ++j) mx = fmaxf(mx, ev[j]);
    mx = fmaxf(mx, __shfl_xor(mx, 16));
    mx = fmaxf(mx, __shfl_xor(mx, 32));
    float sc[8], sm = 0.0f;
    #pragma unroll
    for (int j = 0; j < 8; ++j) { sc[j] = __expf(ev[j] - mx); sm += sc[j]; }
    sm += __shfl_xor(sm, 16); sm += __shfl_xor(sm, 32);
    const float inv = 1.0f / sm;
    #pragma unroll
    for (int j = 0; j < 8; ++j) sc[j] *= inv;

    const int d0 = lane * 8;
    float cx[8];
    #pragma unroll
    for (int j = 0; j < 8; ++j) cx[j] = 0.0f;
    #pragma unroll
    for (int w = 0; w < WW; ++w) {
        int tk = __shfl(my_tok, w);
        float s = __shfl(sc[(w >> 4) * 4 + (w & 3)], ((w >> 2) & 3) * 16);
        const float4* pr = (const float4*)(embf + ((size_t)tk << 9) + d0);
        float4 x0 = pr[0], x1 = pr[1];
        cx[0] += s * x0.x; cx[1] += s * x0.y; cx[2] += s * x0.z; cx[3] += s * x0.w;
        cx[4] += s * x1.x; cx[5] += s * x1.y; cx[6] += s * x1.z; cx[7] += s * x1.w;
    }
    const bool outmask = (n < node_sizes[b * CCC + c]) && (c < cross_lengths[b]);
    if (!outmask) {
        #pragma unroll
        for (int j = 0; j < 8; ++j) cx[j] = 0.0f;
    }
    float4* op = (float4*)(out + (size_t)t * DD + d0);
    op[0] = float4{cx[0], cx[1], cx[2], cx[3]};
    op[1] = float4{cx[4], cx[5], cx[6], cx[7]};
}

extern "C" void kernel_launch(void* const* d_in, const int* in_sizes, int n_in,
                              void* d_out, int out_size, void* d_ws, size_t ws_size,
                              hipStream_t stream) {
    const int*   token_ids     = (const int*)d_in[0];
    const int*   node_lengths  = (const int*)d_in[1];
    const int*   node_sizes    = (const int*)d_in[2];
    const int*   cross_lengths = (const int*)d_in[3];
    const float* con_hidden    = (const float*)d_in[4];
    const float* emb           = (const float*)d_in[5];
    const float* W_pre         = (const float*)d_in[6];
    const float* b_pre         = (const float*)d_in[7];
    const float* W_q           = (const float*)d_in[8];
    const float* v             = (const float*)d_in[9];

    float*  out     = (float*)d_out;
    float*  hid_out = out + (size_t)TB * DD;                  // second output
    float*  q       = (float*)d_ws;                           // 16 KB
    uint2*  wb8     = (uint2*)((char*)d_ws + 16 * 1024);      // 32 KB fp8 frags
    bf16x8* wb      = (bf16x8*)((char*)d_ws + 16 * 1024);     // fallback bf16 frags
    unsigned short* P = (unsigned short*)((char*)d_ws + 80 * 1024);   // 4 MB bf16
    unsigned char* emb8 = (unsigned char*)d_ws + 80 * 1024 + (size_t)VCB * DKK * 2;

    const size_t need = 80 * 1024 + (size_t)VCB * DKK * 2 + (size_t)VCB * DD;

    if (ws_size >= need) {
        prep_pack<<<128, 256, 0, stream>>>(con_hidden, W_q, W_pre, q, hid_out, wb8);
        conv_gemm<<<VCB / 64, 256, 0, stream>>>(emb, emb8, P, wb8);
        bag_kernel<<<TB / 8, 512, 0, stream>>>(
            token_ids, node_lengths, node_sizes, cross_lengths,
            emb8, P, b_pre, v, q, out);
    } else {
        prep_kernel<<<64, 64, 0, stream>>>(con_hidden, W_q, q, hid_out);
        pack_wpre<<<64, 64, 0, stream>>>(W_pre, wb);
        bag_kernel_f32<<<TB / 4, 256, 0, stream>>>(
            token_ids, node_lengths, node_sizes, cross_lengths,
            emb, b_pre, v, q, wb, out);
    }
}

// Round 15
// 65.143 us; speedup vs baseline: 1.4661x; 1.0293x over previous
//
#include <hip/hip_runtime.h>
#include <hip/hip_bf16.h>

#define TB   8192   // B*C*N bags
#define WW   32     // words per bag
#define DD   512    // d_model
#define DKK  64     // attention dim
#define CCC  4      // max cross
#define VCB  32000  // vocab
#define CONVB 500   // conv blocks (64 vocab rows each)

using bf16x8 = __attribute__((ext_vector_type(8))) short;
using f32x4  = __attribute__((ext_vector_type(4))) float;
using f32x2  = __attribute__((ext_vector_type(2))) float;

__device__ __forceinline__ unsigned short f2bf(float x) {
    union { float f; unsigned u; } u;
    u.f = x;
    unsigned r = u.u + 0x7fffu + ((u.u >> 16) & 1u);
    return (unsigned short)(r >> 16);
}

__device__ __forceinline__ bf16x8 make_frag(float4 x, float4 y) {
    union { bf16x8 v; unsigned short s[8]; } u;
    u.s[0] = f2bf(x.x); u.s[1] = f2bf(x.y); u.s[2] = f2bf(x.z); u.s[3] = f2bf(x.w);
    u.s[4] = f2bf(y.x); u.s[5] = f2bf(y.y); u.s[6] = f2bf(y.z); u.s[7] = f2bf(y.w);
    return u.v;
}

// pack 8 fp32 -> 8 fp8 e4m3 (HW cvt, RNE) as uint2; byte j == element j
__device__ __forceinline__ uint2 pack_fp8x8(float4 a, float4 b) {
    int lo = 0, hi = 0;
    lo = __builtin_amdgcn_cvt_pk_fp8_f32(a.x, a.y, lo, false);
    lo = __builtin_amdgcn_cvt_pk_fp8_f32(a.z, a.w, lo, true);
    hi = __builtin_amdgcn_cvt_pk_fp8_f32(b.x, b.y, hi, false);
    hi = __builtin_amdgcn_cvt_pk_fp8_f32(b.z, b.w, hi, true);
    uint2 r; r.x = (unsigned)lo; r.y = (unsigned)hi;
    return r;
}

__device__ __forceinline__ long long u2l(uint2 u) {
    union { uint2 v; long long l; } c; c.v = u; return c.l;
}

// fma 8 fp8 elems into fp32 accumulators: cx[j] += s * elem[j]
__device__ __forceinline__ void fp8x8_fma(float* cx, uint2 r, float s) {
    f32x2 f01 = __builtin_amdgcn_cvt_pk_f32_fp8((int)r.x, false);
    f32x2 f23 = __builtin_amdgcn_cvt_pk_f32_fp8((int)r.x, true);
    f32x2 f45 = __builtin_amdgcn_cvt_pk_f32_fp8((int)r.y, false);
    f32x2 f67 = __builtin_amdgcn_cvt_pk_f32_fp8((int)r.y, true);
    cx[0] += s * f01[0]; cx[1] += s * f01[1];
    cx[2] += s * f23[0]; cx[3] += s * f23[1];
    cx[4] += s * f45[0]; cx[5] += s * f45[1];
    cx[6] += s * f67[0]; cx[7] += s * f67[1];
}

// ---------------- k1: pack W_pre fp8 fragments (tiny) ----------------
__global__ __launch_bounds__(64) void pack8(
    const float* __restrict__ W_pre,       // [512][64]
    uint2* __restrict__ wb8)               // 64 frags * 64 lanes * 8B
{
    const int fb = blockIdx.x;             // ks*4 + nt
    const int tid = threadIdx.x;
    const int ks = fb >> 2, nt = fb & 3;
    const int lr = tid & 15, lg = tid >> 4;
    float w[8];
    #pragma unroll
    for (int j = 0; j < 8; ++j)
        w[j] = W_pre[(ks * 32 + lg * 8 + j) * DKK + nt * 16 + lr];
    wb8[fb * 64 + tid] = pack_fp8x8(float4{w[0], w[1], w[2], w[3]},
                                    float4{w[4], w[5], w[6], w[7]});
}

// ---------------- k2: fused conv fp32->fp8 + P GEMM + (q GEMV, hidden copy) --
// blocks [0, CONVB)      : 64 vocab rows each — convert + MFMA into P (bf16)
// blocks [CONVB, +64)    : q[b,:] GEMV + hidden row copy (overlaps with conv)
__global__ __launch_bounds__(256) void conv_gemm(
    const float* __restrict__ emb,         // [32000][512] fp32
    unsigned char* __restrict__ emb8,      // [32000*512] fp8 out
    unsigned short* __restrict__ P,        // [32000][64] bf16 out
    const uint2* __restrict__ wb8,         // packed W_pre fp8 fragments
    const float* __restrict__ con_hidden,  // [64][512]
    const float* __restrict__ W_q,         // [512][64]
    float* __restrict__ qout,              // [64][64]
    float* __restrict__ hid_out)           // [64][512]
{
    const int blk = blockIdx.x;
    const int tid = threadIdx.x;

    if (blk >= CONVB) {
        // ---- q-GEMV + hidden copy (one block per sample b) ----
        __shared__ float red[256];
        const int b = blk - CONVB;
        const int k = tid & 63, qtr = tid >> 6;
        const float* h = con_hidden + b * DD;
        float acc = 0.0f;
        const int d0 = qtr * 128;
        #pragma unroll 8
        for (int d = 0; d < 128; ++d) acc += h[d0 + d] * W_q[(d0 + d) * DKK + k];
        red[tid] = acc;
        __syncthreads();
        if (tid < 64)
            qout[b * DKK + tid] = red[tid] + red[64 + tid] + red[128 + tid] + red[192 + tid];
        if (tid < 128) {
            const float4* src = (const float4*)h;
            ((float4*)(hid_out + b * DD))[tid] = src[tid];
        }
        return;
    }

    // ---- conv + P GEMM path ----
    const int wid  = tid >> 6;
    const int lane = tid & 63;
    const int lr = lane & 15, lg = lane >> 4;
    const int base = blk * 64 + wid * 16;          // this wave's 16 rows

    __shared__ uint2 swb[4096];   // 32 KB W_pre fp8 fragments
    #pragma unroll
    for (int i = tid; i < 4096; i += 256) swb[i] = wb8[i];
    __syncthreads();

    const float* arow = emb + (size_t)(base + lr) * DD + lg * 8;
    unsigned char* erow = emb8 + (size_t)(base + lr) * DD + lg * 8;

    f32x4 accP[4];
    #pragma unroll
    for (int nt = 0; nt < 4; ++nt) accP[nt] = (f32x4){0.f, 0.f, 0.f, 0.f};

    // 4-deep prefetch on the streaming emb reads (2 waves/SIMD can't hide
    // HBM latency without ILP)
    float4 Fx[4], Fy[4];
    auto eissue = [&](int ks, int sl) {
        const float4* p = (const float4*)(arow + ks * 32);
        Fx[sl] = p[0]; Fy[sl] = p[1];
    };
    eissue(0, 0); eissue(1, 1); eissue(2, 2); eissue(3, 3);
    asm volatile("" ::: "memory");

    #pragma unroll
    for (int ks = 0; ks < 16; ++ks) {
        float4 x = Fx[ks & 3], y = Fy[ks & 3];     // consume before slot reuse
        if (ks + 4 < 16) eissue(ks + 4, ks & 3);
        asm volatile("" ::: "memory");
        uint2 a8 = pack_fp8x8(x, y);
        *(uint2*)(erow + ks * 32) = a8;
        long long a = u2l(a8);
        #pragma unroll
        for (int nt = 0; nt < 4; ++nt) {
            long long bfr = u2l(swb[(ks * 4 + nt) * 64 + lane]);
            accP[nt] = __builtin_amdgcn_mfma_f32_16x16x32_fp8_fp8(a, bfr, accP[nt], 0, 0, 0);
        }
    }

    // C layout: col = nt*16 + lr, row = lg*4 + r
    #pragma unroll
    for (int nt = 0; nt < 4; ++nt)
        #pragma unroll
        for (int r = 0; r < 4; ++r)
            P[(size_t)(base + lg * 4 + r) * DKK + nt * 16 + lr] = f2bf(accP[nt][r]);
}

// ---------------- k3: bag kernel — bf16 P gather + lane-local softmax + fp8 ctx
__global__ __launch_bounds__(512) void bag_kernel(
    const int* __restrict__ token_ids,     // [8192][32]
    const int* __restrict__ node_lengths,  // [8192]
    const int* __restrict__ node_sizes,    // [256]
    const int* __restrict__ cross_lengths, // [64]
    const unsigned char* __restrict__ emb8, // [32000*512] fp8, row 0 zeros
    const unsigned short* __restrict__ P,  // [32000][64] bf16 pre-projections
    const float* __restrict__ b_pre,       // [64]
    const float* __restrict__ v,           // [64]
    const float* __restrict__ q,           // [64][64]
    float* __restrict__ out)               // [8192][512]
{
    const int tid  = threadIdx.x;
    const int wid  = tid >> 6;
    const int lane = tid & 63;             // lane == k index
    const int t = blockIdx.x * 8 + wid;
    const int b = t >> 7, cn = t & 127, c = cn >> 5, n = cn & 31;

    const int L = node_lengths[t];
    const int* toks = token_ids + t * WW;

    int my_tok = 0;
    if (lane < 32 && lane < L) my_tok = toks[lane];   // emb/P row 0 is zero

    const float qb = q[b * DKK + lane] + b_pre[lane];
    const float vv = v[lane];

    // ---- P-row gather (bf16), 8-deep pipeline ----
    unsigned short Pu[8];
    auto pissue = [&](int w, int sl) {
        int tk = __shfl(my_tok, w);
        Pu[sl] = P[(size_t)tk * DKK + lane];
    };
    pissue(0, 0); pissue(1, 1); pissue(2, 2); pissue(3, 3);
    pissue(4, 4); pissue(5, 5); pissue(6, 6); pissue(7, 7);
    asm volatile("" ::: "memory");

    // ---- context-row prefetch starts now (addresses need only my_tok) ----
    const int d0 = lane * 8;
    uint2 R[6];
    auto cissue = [&](int w, int sl) {
        int tk = __shfl(my_tok, w);
        R[sl] = *(const uint2*)(emb8 + ((size_t)tk << 9) + d0);
    };
    cissue(0, 0); cissue(1, 1); cissue(2, 2);
    cissue(3, 3); cissue(4, 4); cissue(5, 5);
    asm volatile("" ::: "memory");

    // ---- energy: e[w] = sum_k tanh(P[tok_w][k] + qb) * v[k]; butterfly
    float sc[32];
    #pragma unroll
    for (int w = 0; w < WW; ++w) {
        float pv = __uint_as_float((unsigned)Pu[w & 7] << 16);
        if (w + 8 < WW) pissue(w + 8, w & 7);
        asm volatile("" ::: "memory");
        float ez = __expf(2.0f * (pv + qb));             // tanh via exp
        float th = 1.0f - 2.0f * __builtin_amdgcn_rcpf(ez + 1.0f);
        float e = th * vv;
        e += __shfl_xor(e, 1);  e += __shfl_xor(e, 2);
        e += __shfl_xor(e, 4);  e += __shfl_xor(e, 8);
        e += __shfl_xor(e, 16); e += __shfl_xor(e, 32);
        sc[w] = e;
    }

    // ---- softmax over the 32 energies (replicated in-lane) ----
    float mx = sc[0];
    #pragma unroll
    for (int j = 1; j < 32; ++j) mx = fmaxf(mx, sc[j]);
    float sm = 0.0f;
    #pragma unroll
    for (int j = 0; j < 32; ++j) { sc[j] = __expf(sc[j] - mx); sm += sc[j]; }
    const float inv = 1.0f / sm;
    #pragma unroll
    for (int j = 0; j < 32; ++j) sc[j] *= inv;

    // ---- context: lane owns 8 consecutive d's; 6-deep fp8 gather ----
    float cx[8];
    #pragma unroll
    for (int j = 0; j < 8; ++j) cx[j] = 0.0f;

    #pragma unroll
    for (int w = 0; w < WW; ++w) {
        uint2 r = R[w % 6];
        float s = sc[w];
        if (w + 6 < WW) cissue(w + 6, (w + 6) % 6);
        asm volatile("" ::: "memory");
        fp8x8_fma(cx, r, s);
    }

    const bool outmask = (n < node_sizes[b * CCC + c]) && (c < cross_lengths[b]);
    if (!outmask) {
        #pragma unroll
        for (int j = 0; j < 8; ++j) cx[j] = 0.0f;
    }
    float4* op = (float4*)(out + (size_t)t * DD + d0);
    op[0] = float4{cx[0], cx[1], cx[2], cx[3]};
    op[1] = float4{cx[4], cx[5], cx[6], cx[7]};
}

// ---------------- fp32/bf16 fallback (ws too small; not expected) ----------
__global__ __launch_bounds__(64) void prep_kernel(
    const float* __restrict__ con_hidden, const float* __restrict__ W_q,
    float* __restrict__ qout, float* __restrict__ hid_out)
{
    const int b = blockIdx.x;
    const int k = threadIdx.x;
    const float* h = con_hidden + b * DD;
    float acc = 0.0f;
    #pragma unroll 8
    for (int d = 0; d < DD; ++d) acc += h[d] * W_q[d * DKK + k];
    qout[b * DKK + k] = acc;
    const float4* src = (const float4*)h;
    float4* dst = (float4*)(hid_out + b * DD);
    for (int i = k; i < DD / 4; i += 64) dst[i] = src[i];
}

__global__ __launch_bounds__(64) void pack_wpre(
    const float* __restrict__ W_pre, bf16x8* __restrict__ wb)
{
    const int blk = blockIdx.x;
    const int ks = blk >> 2, nt = blk & 3;
    const int l  = threadIdx.x;
    const int lr = l & 15, lg = l >> 4;
    union { bf16x8 v; unsigned short s[8]; } u;
    #pragma unroll
    for (int j = 0; j < 8; ++j) {
        int k = ks * 32 + lg * 8 + j;
        u.s[j] = f2bf(W_pre[k * DKK + nt * 16 + lr]);
    }
    wb[blk * 64 + l] = u.v;
}

__global__ __launch_bounds__(256) void bag_kernel_f32(
    const int* __restrict__ token_ids, const int* __restrict__ node_lengths,
    const int* __restrict__ node_sizes, const int* __restrict__ cross_lengths,
    const float* __restrict__ embf, const float* __restrict__ b_pre,
    const float* __restrict__ v, const float* __restrict__ q,
    const bf16x8* __restrict__ wb, float* __restrict__ out)
{
    const int wid  = threadIdx.x >> 6;
    const int lane = threadIdx.x & 63;
    const int t = blockIdx.x * 4 + wid;
    const int b = t >> 7, cn = t & 127, c = cn >> 5, n = cn & 31;
    const int lr = lane & 15, lg = lane >> 4;

    const int L = node_lengths[t];
    const int* toks = token_ids + t * WW;
    int my_tok = 0;
    if (lane < 32 && lane < L) my_tok = toks[lane];
    const int tok0 = __shfl(my_tok, lr);
    const int tok1 = __shfl(my_tok, 16 + lr);
    const float* fp0 = embf + ((size_t)tok0 << 9) + lg * 8;
    const float* fp1 = embf + ((size_t)tok1 << 9) + lg * 8;

    f32x4 acc[2][4];
    #pragma unroll
    for (int mt = 0; mt < 2; ++mt)
        #pragma unroll
        for (int nt = 0; nt < 4; ++nt)
            acc[mt][nt] = (f32x4){0.f, 0.f, 0.f, 0.f};

    #pragma unroll 4
    for (int ks = 0; ks < 16; ++ks) {
        const float4* a0p = (const float4*)(fp0 + ks * 32);
        const float4* a1p = (const float4*)(fp1 + ks * 32);
        bf16x8 a0 = make_frag(a0p[0], a0p[1]);
        bf16x8 a1 = make_frag(a1p[0], a1p[1]);
        #pragma unroll
        for (int nt = 0; nt < 4; ++nt) {
            bf16x8 bb = wb[(ks * 4 + nt) * 64 + lane];
            acc[0][nt] = __builtin_amdgcn_mfma_f32_16x16x32_bf16(a0, bb, acc[0][nt], 0, 0, 0);
            acc[1][nt] = __builtin_amdgcn_mfma_f32_16x16x32_bf16(a1, bb, acc[1][nt], 0, 0, 0);
        }
    }

    float qb[4], vv[4];
    #pragma unroll
    for (int nt = 0; nt < 4; ++nt) {
        int cidx = nt * 16 + lr;
        qb[nt] = q[b * DKK + cidx] + b_pre[cidx];
        vv[nt] = v[cidx];
    }
    float ev[8];
    #pragma unroll
    for (int mt = 0; mt < 2; ++mt) {
        #pragma unroll
        for (int r = 0; r < 4; ++r) {
            float s = 0.0f;
            #pragma unroll
            for (int nt = 0; nt < 4; ++nt) {
                float pre = acc[mt][nt][r] + qb[nt];
                float ez = __expf(2.0f * pre);
                float th = 1.0f - 2.0f * __builtin_amdgcn_rcpf(ez + 1.0f);
                s += th * vv[nt];
            }
            s += __shfl_xor(s, 1); s += __shfl_xor(s, 2);
            s += __shfl_xor(s, 4); s += __shfl_xor(s, 8);
            ev[mt * 4 + r] = s;
        }
    }
    float mx = ev[0];
    #pragma unroll
    for (int j = 1; j < 8; ++j) mx = fmaxf(mx, ev[j]);
    mx = fmaxf(mx, __shfl_xor(mx, 16));
    mx = fmaxf(mx, __shfl_xor(mx, 32));
    float sc[8], sm = 0.0f;
    #pragma unroll
    for (int j = 0; j < 8; ++j) { sc[j] = __expf(ev[j] - mx); sm += sc[j]; }
    sm += __shfl_xor(sm, 16); sm += __shfl_xor(sm, 32);
    const float inv = 1.0f / sm;
    #pragma unroll
    for (int j = 0; j < 8; ++j) sc[j] *= inv;

    const int d0 = lane * 8;
    float cx[8];
    #pragma unroll
    for (int j = 0; j < 8; ++j) cx[j] = 0.0f;
    #pragma unroll
    for (int w = 0; w < WW; ++w) {
        int tk = __shfl(my_tok, w);
        float s = __shfl(sc[(w >> 4) * 4 + (w & 3)], ((w >> 2) & 3) * 16);
        const float4* pr = (const float4*)(embf + ((size_t)tk << 9) + d0);
        float4 x0 = pr[0], x1 = pr[1];
        cx[0] += s * x0.x; cx[1] += s * x0.y; cx[2] += s * x0.z; cx[3] += s * x0.w;
        cx[4] += s * x1.x; cx[5] += s * x1.y; cx[6] += s * x1.z; cx[7] += s * x1.w;
    }
    const bool outmask = (n < node_sizes[b * CCC + c]) && (c < cross_lengths[b]);
    if (!outmask) {
        #pragma unroll
        for (int j = 0; j < 8; ++j) cx[j] = 0.0f;
    }
    float4* op = (float4*)(out + (size_t)t * DD + d0);
    op[0] = float4{cx[0], cx[1], cx[2], cx[3]};
    op[1] = float4{cx[4], cx[5], cx[6], cx[7]};
}

extern "C" void kernel_launch(void* const* d_in, const int* in_sizes, int n_in,
                              void* d_out, int out_size, void* d_ws, size_t ws_size,
                              hipStream_t stream) {
    const int*   token_ids     = (const int*)d_in[0];
    const int*   node_lengths  = (const int*)d_in[1];
    const int*   node_sizes    = (const int*)d_in[2];
    const int*   cross_lengths = (const int*)d_in[3];
    const float* con_hidden    = (const float*)d_in[4];
    const float* emb           = (const float*)d_in[5];
    const float* W_pre         = (const float*)d_in[6];
    const float* b_pre         = (const float*)d_in[7];
    const float* W_q           = (const float*)d_in[8];
    const float* v             = (const float*)d_in[9];

    float*  out     = (float*)d_out;
    float*  hid_out = out + (size_t)TB * DD;                  // second output
    float*  q       = (float*)d_ws;                           // 16 KB
    uint2*  wb8     = (uint2*)((char*)d_ws + 16 * 1024);      // 32 KB fp8 frags
    bf16x8* wb      = (bf16x8*)((char*)d_ws + 16 * 1024);     // fallback bf16 frags
    unsigned short* P = (unsigned short*)((char*)d_ws + 80 * 1024);   // 4 MB bf16
    unsigned char* emb8 = (unsigned char*)d_ws + 80 * 1024 + (size_t)VCB * DKK * 2;

    const size_t need = 80 * 1024 + (size_t)VCB * DKK * 2 + (size_t)VCB * DD;

    if (ws_size >= need) {
        pack8<<<64, 64, 0, stream>>>(W_pre, wb8);
        conv_gemm<<<CONVB + 64, 256, 0, stream>>>(
            emb, emb8, P, wb8, con_hidden, W_q, q, hid_out);
        bag_kernel<<<TB / 8, 512, 0, stream>>>(
            token_ids, node_lengths, node_sizes, cross_lengths,
            emb8, P, b_pre, v, q, out);
    } else {
        prep_kernel<<<64, 64, 0, stream>>>(con_hidden, W_q, q, hid_out);
        pack_wpre<<<64, 64, 0, stream>>>(W_pre, wb);
        bag_kernel_f32<<<TB / 4, 256, 0, stream>>>(
            token_ids, node_lengths, node_sizes, cross_lengths,
            emb, b_pre, v, q, wb, out);
    }
}